// Round 19
// baseline (827.114 us; speedup 1.0000x reference)
//
#include <hip/hip_runtime.h>

#define S_LEN 2048
#define DMODEL 2048
#define NH 16
#define NKV 4
#define HD 128
#define NE 8
#define FF 2048
#define QKV_N 3072   // (H + 2*KV) * HD

typedef __attribute__((ext_vector_type(8))) short short8;
typedef __attribute__((ext_vector_type(4))) float f32x4;

__device__ inline unsigned short f2bf(float f) {
  unsigned int u = __builtin_bit_cast(unsigned int, f);
  u += 0x7fffu + ((u >> 16) & 1u);
  return (unsigned short)(u >> 16);
}
__device__ inline float bf2f(unsigned short h) {
  unsigned int u = ((unsigned int)h) << 16;
  return __builtin_bit_cast(float, u);
}
__device__ inline void split2(float v, unsigned short& h, unsigned short& l) {
  h = f2bf(v);
  l = f2bf(v - bf2f(h));
}

// ======== chunk format (verified r3-r18): 8KB = 128 rows x 32 k bf16 ========
// element (row, k=8q+j) at ushort off row*32 + ((q ^ s(row))<<3) + j, s=(row^(row>>2))&3

__device__ inline void gload16(const void* g, void* l) {
  __builtin_amdgcn_global_load_lds((const __attribute__((address_space(1))) unsigned int*)g,
                                   (__attribute__((address_space(3))) unsigned int*)l,
                                   16, 0, 0);
}
// 256-thread cooperative full-chunk stage (2 gloads/lane)
__device__ inline void stageB_chunk(const unsigned short* __restrict__ chunk,
                                    unsigned short* __restrict__ lds) {
  int w = threadIdx.x >> 6, l = threadIdx.x & 63;
  const unsigned short* s = chunk + w * 1024 + l * 8;
  unsigned short* d = lds + w * 1024;
  gload16(s, d);
  gload16(s + 512, d + 512);
}
// 512-thread cooperative full-chunk stage (1 gload/lane)
__device__ inline void stageB_chunk8(const unsigned short* __restrict__ chunk,
                                     unsigned short* __restrict__ lds) {
  int w = threadIdx.x >> 6, l = threadIdx.x & 63;
  gload16(chunk + w * 512 + l * 8, lds + w * 512);
}

#define WVM0   asm volatile("s_waitcnt vmcnt(0)" ::: "memory")
#define WVM3   asm volatile("s_waitcnt vmcnt(3)" ::: "memory")
#define WVM4   asm volatile("s_waitcnt vmcnt(4)" ::: "memory")
#define WVM6   asm volatile("s_waitcnt vmcnt(6)" ::: "memory")
#define WVM8   asm volatile("s_waitcnt vmcnt(8)" ::: "memory")
#define WVM12  asm volatile("s_waitcnt vmcnt(12)" ::: "memory")
#define WAIT_ALL  asm volatile("s_waitcnt vmcnt(0) lgkmcnt(0)" ::: "memory")
#define WAIT_LDS  asm volatile("s_waitcnt lgkmcnt(0)" ::: "memory")
#define SCHEDBAR  __builtin_amdgcn_sched_barrier(0)
#define BAR       __builtin_amdgcn_s_barrier()

// ---------------- MFMA cores ----------------

__device__ inline void mma16(const unsigned short* As, const unsigned short* Bs,
                             int wr, int wc, f32x4 acc[4][4]) {
  int l = threadIdx.x & 63;
  int lr = l & 15, lg = l >> 4;
  int qoff = ((lg ^ ((lr ^ (lr >> 2)) & 3)) << 3);
  short8 a[4], b[4];
#pragma unroll
  for (int m = 0; m < 4; m++)
    a[m] = *(const short8*)(As + (wr + m * 16 + lr) * 32 + qoff);
#pragma unroll
  for (int n = 0; n < 4; n++)
    b[n] = *(const short8*)(Bs + (wc + n * 16 + lr) * 32 + qoff);
#pragma unroll
  for (int m = 0; m < 4; m++)
#pragma unroll
    for (int n = 0; n < 4; n++)
      acc[m][n] = __builtin_amdgcn_mfma_f32_16x16x32_bf16(a[m], b[n], acc[m][n], 0, 0, 0);
}

// 8-wave variant: wave computes 32x64 (2 m-frags x 4 n-frags), dual B
__device__ inline void mma16_dualB24(const unsigned short* As, const unsigned short* Bs1,
                                     const unsigned short* Bs2, int wr, int wc,
                                     f32x4 acc1[2][4], f32x4 acc2[2][4]) {
  int l = threadIdx.x & 63;
  int lr = l & 15, lg = l >> 4;
  int qoff = ((lg ^ ((lr ^ (lr >> 2)) & 3)) << 3);
  short8 a[2], b1[4], b2[4];
#pragma unroll
  for (int m = 0; m < 2; m++)
    a[m] = *(const short8*)(As + (wr + m * 16 + lr) * 32 + qoff);
#pragma unroll
  for (int n = 0; n < 4; n++) {
    b1[n] = *(const short8*)(Bs1 + (wc + n * 16 + lr) * 32 + qoff);
    b2[n] = *(const short8*)(Bs2 + (wc + n * 16 + lr) * 32 + qoff);
  }
#pragma unroll
  for (int m = 0; m < 2; m++)
#pragma unroll
    for (int n = 0; n < 4; n++) {
      acc1[m][n] = __builtin_amdgcn_mfma_f32_16x16x32_bf16(a[m], b1[n], acc1[m][n], 0, 0, 0);
      acc2[m][n] = __builtin_amdgcn_mfma_f32_16x16x32_bf16(a[m], b2[n], acc2[m][n], 0, 0, 0);
    }
}

__device__ inline void mma16_split_reg(const unsigned short* Ash, const unsigned short* Asl,
                                       const unsigned short* Bsh, const unsigned short* Bsl,
                                       int wr, int wc, f32x4 acc[4][4]) {
  int l = threadIdx.x & 63;
  int lr = l & 15, lg = l >> 4;
  int qoff = ((lg ^ ((lr ^ (lr >> 2)) & 3)) << 3);
  short8 ah[4], al[4], bh[4], bl[4];
#pragma unroll
  for (int m = 0; m < 4; m++) {
    ah[m] = *(const short8*)(Ash + (wr + m * 16 + lr) * 32 + qoff);
    al[m] = *(const short8*)(Asl + (wr + m * 16 + lr) * 32 + qoff);
  }
#pragma unroll
  for (int n = 0; n < 4; n++) {
    bh[n] = *(const short8*)(Bsh + (wc + n * 16 + lr) * 32 + qoff);
    bl[n] = *(const short8*)(Bsl + (wc + n * 16 + lr) * 32 + qoff);
  }
#pragma unroll
  for (int m = 0; m < 4; m++)
#pragma unroll
    for (int n = 0; n < 4; n++) {
      acc[m][n] = __builtin_amdgcn_mfma_f32_16x16x32_bf16(ah[m], bh[n], acc[m][n], 0, 0, 0);
      acc[m][n] = __builtin_amdgcn_mfma_f32_16x16x32_bf16(ah[m], bl[n], acc[m][n], 0, 0, 0);
      acc[m][n] = __builtin_amdgcn_mfma_f32_16x16x32_bf16(al[m], bh[n], acc[m][n], 0, 0, 0);
    }
}

// ---------------- pack kernels ----------------

__global__ __launch_bounds__(256) void k_pack1(const float* __restrict__ src, long ld,
                                               long zs, int nc,
                                               unsigned short* __restrict__ dst) {
  __shared__ float tile[32][132];
  const float* Sp = src + (long)blockIdx.z * zs;
  int c = blockIdx.x, t = threadIdx.x;
  for (int i = 0; i < 4; i++) {
    int kt = blockIdx.y * 4 + i;
    long k0 = (long)kt * 32, n0 = (long)c * 128;
    {
      int k = t >> 3, nn = (t & 7) * 16;
      const float4* p = (const float4*)(Sp + (k0 + k) * ld + n0 + nn);
#pragma unroll
      for (int j = 0; j < 4; j++) *(float4*)&tile[k][nn + j * 4] = p[j];
    }
    __syncthreads();
    size_t cbase = ((size_t)(blockIdx.z * nc + c) * 64 + kt) * 4096;
#pragma unroll
    for (int uu = 0; uu < 2; uu++) {
      int u = t * 2 + uu;
      int n = u >> 2, qp = u & 3;
      int q = qp ^ ((n ^ (n >> 2)) & 3);
      unsigned short hb[8] __attribute__((aligned(16)));
#pragma unroll
      for (int j = 0; j < 8; j++) hb[j] = f2bf(tile[8 * q + j][n]);
      *(uint4*)(dst + cbase + u * 8) = *(const uint4*)hb;
    }
    __syncthreads();
  }
}

__global__ __launch_bounds__(256) void k_pack2(const float* __restrict__ src, long ld,
                                               long zs, int nc,
                                               unsigned short* __restrict__ dh,
                                               unsigned short* __restrict__ dl) {
  __shared__ float tile[32][132];
  const float* Sp = src + (long)blockIdx.z * zs;
  int c = blockIdx.x, t = threadIdx.x;
  for (int i = 0; i < 4; i++) {
    int kt = blockIdx.y * 4 + i;
    long k0 = (long)kt * 32, n0 = (long)c * 128;
    {
      int k = t >> 3, nn = (t & 7) * 16;
      const float4* p = (const float4*)(Sp + (k0 + k) * ld + n0 + nn);
#pragma unroll
      for (int j = 0; j < 4; j++) *(float4*)&tile[k][nn + j * 4] = p[j];
    }
    __syncthreads();
    size_t cbase = ((size_t)(blockIdx.z * nc + c) * 64 + kt) * 4096;
#pragma unroll
    for (int uu = 0; uu < 2; uu++) {
      int u = t * 2 + uu;
      int n = u >> 2, qp = u & 3;
      int q = qp ^ ((n ^ (n >> 2)) & 3);
      unsigned short hb[8] __attribute__((aligned(16)));
      unsigned short lb[8] __attribute__((aligned(16)));
#pragma unroll
      for (int j = 0; j < 8; j++) split2(tile[8 * q + j][n], hb[j], lb[j]);
      *(uint4*)(dh + cbase + u * 8) = *(const uint4*)hb;
      *(uint4*)(dl + cbase + u * 8) = *(const uint4*)lb;
    }
    __syncthreads();
  }
}

// ---------------- qkv / wo GEMMs (r15/r16 form) ----------------

__global__ __launch_bounds__(256) void k_qkv_s(const unsigned short* __restrict__ APh,
                                               const unsigned short* __restrict__ APl,
                                               const unsigned short* __restrict__ BPh,
                                               const unsigned short* __restrict__ BPl,
                                               float* __restrict__ C) {
  __shared__ unsigned short Ash[2 * 4096], Asl[2 * 4096], Bsh[2 * 4096], Bsl[2 * 4096];
  size_t ab = (size_t)blockIdx.y * 64 * 4096;
  size_t cb = (size_t)blockIdx.x * 64 * 4096;
  int w = threadIdx.x >> 6;
  int wr = (w >> 1) * 64, wc = (w & 1) * 64;
#pragma unroll
  for (int p = 0; p < 2; p++) {
    size_t o = (size_t)p * 4096;
    int b = p << 12;
    stageB_chunk(APh + ab + o, Ash + b);
    stageB_chunk(APl + ab + o, Asl + b);
    stageB_chunk(BPh + cb + o, Bsh + b);
    stageB_chunk(BPl + cb + o, Bsl + b);
  }
  WVM8;
  BAR;
  f32x4 acc[4][4] = {};
  for (int kt = 0; kt < 64; kt++) {
    int cur = (kt & 1) << 12;
    SCHEDBAR;
    mma16_split_reg(Ash + cur, Asl + cur, Bsh + cur, Bsl + cur, wr, wc, acc);
    SCHEDBAR;
    BAR;
    if (kt + 2 < 64) {
      size_t o = (size_t)(kt + 2) * 4096;
      stageB_chunk(APh + ab + o, Ash + cur);
      stageB_chunk(APl + ab + o, Asl + cur);
      stageB_chunk(BPh + cb + o, Bsh + cur);
      stageB_chunk(BPl + cb + o, Bsl + cur);
      WVM8;
    } else {
      WVM0;
    }
    BAR;
  }
  int row0 = blockIdx.y * 128, col0 = blockIdx.x * 128;
  int l = threadIdx.x & 63;
  int er = wr + ((l >> 4) << 2), ec = wc + (l & 15);
#pragma unroll
  for (int m = 0; m < 4; m++)
#pragma unroll
    for (int n = 0; n < 4; n++)
#pragma unroll
      for (int r = 0; r < 4; r++) {
        float v = acc[m][n][r];
        v = fminf(fmaxf(v, -8.f), 8.f);
        C[(size_t)(row0 + er + m * 16 + r) * QKV_N + col0 + ec + n * 16] = v;
      }
}

__global__ __launch_bounds__(256) void k_wo_s(const unsigned short* __restrict__ APh,
                                              const unsigned short* __restrict__ APl,
                                              const unsigned short* __restrict__ BPh,
                                              const unsigned short* __restrict__ BPl,
                                              const float* __restrict__ resid,
                                              float* __restrict__ x1) {
  __shared__ unsigned short Ash[2 * 4096], Asl[2 * 4096], Bsh[2 * 4096], Bsl[2 * 4096];
  size_t ab = (size_t)blockIdx.y * 64 * 4096;
  size_t cb = (size_t)blockIdx.x * 64 * 4096;
  int w = threadIdx.x >> 6;
  int wr = (w >> 1) * 64, wc = (w & 1) * 64;
#pragma unroll
  for (int p = 0; p < 2; p++) {
    size_t o = (size_t)p * 4096;
    int b = p << 12;
    stageB_chunk(APh + ab + o, Ash + b);
    stageB_chunk(APl + ab + o, Asl + b);
    stageB_chunk(BPh + cb + o, Bsh + b);
    stageB_chunk(BPl + cb + o, Bsl + b);
  }
  WVM8;
  BAR;
  f32x4 acc[4][4] = {};
  for (int kt = 0; kt < 64; kt++) {
    int cur = (kt & 1) << 12;
    SCHEDBAR;
    mma16_split_reg(Ash + cur, Asl + cur, Bsh + cur, Bsl + cur, wr, wc, acc);
    SCHEDBAR;
    BAR;
    if (kt + 2 < 64) {
      size_t o = (size_t)(kt + 2) * 4096;
      stageB_chunk(APh + ab + o, Ash + cur);
      stageB_chunk(APl + ab + o, Asl + cur);
      stageB_chunk(BPh + cb + o, Bsh + cur);
      stageB_chunk(BPl + cb + o, Bsl + cur);
      WVM8;
    } else {
      WVM0;
    }
    BAR;
  }
  int row0 = blockIdx.y * 128, col0 = blockIdx.x * 128;
  int l = threadIdx.x & 63;
  int er = wr + ((l >> 4) << 2), ec = wc + (l & 15);
#pragma unroll
  for (int m = 0; m < 4; m++)
#pragma unroll
    for (int n = 0; n < 4; n++)
#pragma unroll
      for (int r = 0; r < 4; r++) {
        size_t idx = (size_t)(row0 + er + m * 16 + r) * DMODEL + col0 + ec + n * 16;
        x1[idx] = resid[idx] + acc[m][n][r];
      }
}

// ---------------- flash attention: r18 core + hoisted Q fragments ----------------
// grid 1024; block 128 thr = 2 waves; BOTH waves cover the same 32 Q rows;
// wave w handles kt = w, w+2, ...  States merged exactly at the end via LDS.

__global__ __launch_bounds__(128, 2) void k_flash(const unsigned short* __restrict__ qh,
                                                  const unsigned short* __restrict__ ql,
                                                  const unsigned short* __restrict__ kPh,
                                                  const unsigned short* __restrict__ kPl,
                                                  const unsigned short* __restrict__ vPh,
                                                  const unsigned short* __restrict__ vPl,
                                                  unsigned short* __restrict__ atPh,
                                                  unsigned short* __restrict__ atPl) {
  int bid = blockIdx.x;
  int h = (bid & 7) | ((bid >> 9) << 3);
  int rt = (bid >> 3) & 63;
  int kv = h >> 2;
  int ntiles = (rt >> 2) + 1;
  __shared__ float Pds[2][32 * 132];  // per-wave P scratch; reused as merge buffer
  int t = threadIdx.x;
  int w = t >> 6, l = t & 63;
  int lr = l & 15, lg = l >> 4;
  int qoff = ((lg ^ ((lr ^ (lr >> 2)) & 3)) << 3);
  int wrow0 = rt * 32;  // both waves: same 32 rows
  const unsigned short* Qbh = qh + (size_t)h * S_LEN * HD;
  const unsigned short* Qbl = ql + (size_t)h * S_LEN * HD;
  const unsigned short* Kch = kPh + (size_t)kv * 64 * 4096;
  const unsigned short* Kcl = kPl + (size_t)kv * 64 * 4096;
  const unsigned short* Vch = vPh + (size_t)kv * 64 * 4096;
  const unsigned short* Vcl = vPl + (size_t)kv * 64 * 4096;
  float* Pw = &Pds[w][0];
  float mrun[2][4], lrun[2][4];
  f32x4 Oc[2][8];
#pragma unroll
  for (int m = 0; m < 2; m++)
#pragma unroll
    for (int r = 0; r < 4; r++) { mrun[m][r] = -3.4e38f; lrun[m][r] = 0.f; }
#pragma unroll
  for (int m = 0; m < 2; m++)
#pragma unroll
    for (int n = 0; n < 8; n++)
#pragma unroll
      for (int r = 0; r < 4; r++) Oc[m][n][r] = 0.f;
  const float scale = 0.08838834764831845f;

  // hoisted loop-invariant Q fragments: [m][kst], hi/lo
  short8 qfh[2][4], qfl[2][4];
#pragma unroll
  for (int m = 0; m < 2; m++)
#pragma unroll
    for (int kst = 0; kst < 4; kst++) {
      size_t o = (size_t)(wrow0 + m * 16 + lr) * HD + kst * 32 + lg * 8;
      qfh[m][kst] = *(const short8*)(Qbh + o);
      qfl[m][kst] = *(const short8*)(Qbl + o);
    }

  for (int kt = w; kt < ntiles; kt += 2) {
    f32x4 Sa[2][8];
#pragma unroll
    for (int m = 0; m < 2; m++)
#pragma unroll
      for (int n = 0; n < 8; n++)
#pragma unroll
        for (int r = 0; r < 4; r++) Sa[m][n][r] = 0.f;
#pragma unroll
    for (int kst = 0; kst < 4; kst++) {
      const unsigned short* Kh = Kch + (size_t)(kt * 4 + kst) * 4096;
      const unsigned short* Kl = Kcl + (size_t)(kt * 4 + kst) * 4096;
      short8 bh[8], bl[8];
#pragma unroll
      for (int n = 0; n < 8; n++) {
        bh[n] = *(const short8*)(Kh + (n * 16 + lr) * 32 + qoff);
        bl[n] = *(const short8*)(Kl + (n * 16 + lr) * 32 + qoff);
      }
#pragma unroll
      for (int m = 0; m < 2; m++)
#pragma unroll
        for (int n = 0; n < 8; n++) {
          Sa[m][n] = __builtin_amdgcn_mfma_f32_16x16x32_bf16(qfh[m][kst], bh[n], Sa[m][n], 0, 0, 0);
          Sa[m][n] = __builtin_amdgcn_mfma_f32_16x16x32_bf16(qfh[m][kst], bl[n], Sa[m][n], 0, 0, 0);
          Sa[m][n] = __builtin_amdgcn_mfma_f32_16x16x32_bf16(qfl[m][kst], bh[n], Sa[m][n], 0, 0, 0);
        }
    }
#pragma unroll
    for (int m = 0; m < 2; m++)
#pragma unroll
      for (int r = 0; r < 4; r++) {
        int row = wrow0 + m * 16 + lg * 4 + r;
        float mx = mrun[m][r];
#pragma unroll
        for (int n = 0; n < 8; n++) {
          float v = Sa[m][n][r] * scale;
          int col = kt * 128 + n * 16 + lr;
          v = (col <= row) ? v : -3.4e38f;
          Sa[m][n][r] = v;
          mx = fmaxf(mx, v);
        }
        mx = fmaxf(mx, __shfl_xor(mx, 1));
        mx = fmaxf(mx, __shfl_xor(mx, 2));
        mx = fmaxf(mx, __shfl_xor(mx, 4));
        mx = fmaxf(mx, __shfl_xor(mx, 8));
        float al_ = expf(mrun[m][r] - mx);
        float sum = 0.f;
#pragma unroll
        for (int n = 0; n < 8; n++) {
          float v = Sa[m][n][r];
          float e = (v > -1.0e37f) ? expf(v - mx) : 0.f;
          Sa[m][n][r] = e;
          sum += e;
        }
        sum += __shfl_xor(sum, 1);
        sum += __shfl_xor(sum, 2);
        sum += __shfl_xor(sum, 4);
        sum += __shfl_xor(sum, 8);
        lrun[m][r] = lrun[m][r] * al_ + sum;
        mrun[m][r] = mx;
#pragma unroll
        for (int n = 0; n < 8; n++) Oc[m][n][r] *= al_;
      }
    WAIT_LDS;
    SCHEDBAR;
#pragma unroll
    for (int m = 0; m < 2; m++)
#pragma unroll
      for (int n = 0; n < 8; n++)
#pragma unroll
        for (int r = 0; r < 4; r++)
          Pw[(m * 16 + lg * 4 + r) * 132 + n * 16 + lr] = Sa[m][n][r];
    WAIT_LDS;
    SCHEDBAR;
#pragma unroll
    for (int kst = 0; kst < 4; kst++) {
      const unsigned short* Vh = Vch + (size_t)(kt * 4 + kst) * 4096;
      const unsigned short* Vl = Vcl + (size_t)(kt * 4 + kst) * 4096;
      short8 bh[8], bl[8];
#pragma unroll
      for (int n = 0; n < 8; n++) {
        bh[n] = *(const short8*)(Vh + (n * 16 + lr) * 32 + qoff);
        bl[n] = *(const short8*)(Vl + (n * 16 + lr) * 32 + qoff);
      }
#pragma unroll
      for (int m = 0; m < 2; m++) {
        const float* pp = &Pw[(m * 16 + lr) * 132 + kst * 32 + lg * 8];
        unsigned short ahb[8] __attribute__((aligned(16)));
        unsigned short alb[8] __attribute__((aligned(16)));
#pragma unroll
        for (int j = 0; j < 8; j++) split2(pp[j], ahb[j], alb[j]);
        short8 ah = *(const short8*)ahb;
        short8 al_ = *(const short8*)alb;
#pragma unroll
        for (int n = 0; n < 8; n++) {
          Oc[m][n] = __builtin_amdgcn_mfma_f32_16x16x32_bf16(ah, bh[n], Oc[m][n], 0, 0, 0);
          Oc[m][n] = __builtin_amdgcn_mfma_f32_16x16x32_bf16(ah, bl[n], Oc[m][n], 0, 0, 0);
          Oc[m][n] = __builtin_amdgcn_mfma_f32_16x16x32_bf16(al_, bh[n], Oc[m][n], 0, 0, 0);
        }
      }
    }
  }
  // ---- merge wave1's partial state into wave0, then epilogue (wave0 only) ----
  __syncthreads();
  if (w == 1) {
#pragma unroll
    for (int m = 0; m < 2; m++) {
      int rowl = m * 16 + lg * 4;
#pragma unroll
      for (int n = 0; n < 8; n++)
#pragma unroll
        for (int r = 0; r < 4; r++)
          Pds[1][(rowl + r) * 132 + n * 16 + lr] = Oc[m][n][r];
      if (lr == 0) {
#pragma unroll
        for (int r = 0; r < 4; r++) {
          Pds[0][rowl + r] = mrun[m][r];
          Pds[0][32 + rowl + r] = lrun[m][r];
        }
      }
    }
  }
  __syncthreads();
  if (w == 0) {
#pragma unroll
    for (int m = 0; m < 2; m++)
#pragma unroll
      for (int r = 0; r < 4; r++) {
        int rowl = m * 16 + lg * 4 + r;
        int row = wrow0 + rowl;
        float mB = Pds[0][rowl];
        float lB = Pds[0][32 + rowl];
        float mm = fmaxf(mrun[m][r], mB);
        float eA = expf(mrun[m][r] - mm);
        float eB = (mB > -1.0e37f) ? expf(mB - mm) : 0.f;
        float lv = lrun[m][r] * eA + lB * eB;
        int rtc = row >> 7, rl = row & 127;
        int sr = (rl ^ (rl >> 2)) & 3;
#pragma unroll
        for (int n = 0; n < 8; n++) {
          float ov = Oc[m][n][r] * eA + Pds[1][rowl * 132 + n * 16 + lr] * eB;
          int col = h * HD + n * 16 + lr;
          size_t off = ((size_t)(rtc * 64 + (col >> 5))) * 4096 + rl * 32 +
                       ((((col & 31) >> 3) ^ sr) << 3) + (col & 7);
          unsigned short hh, ll;
          split2(ov / lv, hh, ll);
          atPh[off] = hh;
          atPl[off] = ll;
        }
      }
  }
}

// ---------------- MoE GEMMs ----------------

// moe1f: 8-wave (512 thr), wave = 32x64 quadrant; depth-3 counted vmcnt
__global__ __launch_bounds__(512, 4) void k_moe1f(const unsigned short* __restrict__ h2b,
                                                  const int* __restrict__ ptok,
                                                  const unsigned short* __restrict__ wPa,
                                                  const unsigned short* __restrict__ wPb,
                                                  const int* __restrict__ meta,
                                                  unsigned short* __restrict__ g) {
  int ty = blockIdx.y;
  if (ty >= meta[25]) return;
  int tt = meta[26 + ty];
  int e = tt & 7, m0 = tt >> 3;
  int nvalid = min(128, meta[e] - m0);
  const unsigned short* B1 = wPa + (size_t)(e * 16 + blockIdx.x) * 64 * 4096;
  const unsigned short* B2 = wPb + (size_t)(e * 16 + blockIdx.x) * 64 * 4096;
  __shared__ unsigned short L[3][3][4096];  // 72KB
  int tid = threadIdx.x;
  int w = tid >> 6;
  int lid = tid & 63;
  int wr = (w & 3) * 32, wc = (w >> 2) * 64;
  int r0 = w * 16 + (lid >> 2);
  int qx = lid & 3;
  int s0 = (r0 ^ (r0 >> 2)) & 3;
  long pb = (long)meta[16 + e] + m0;
  int tk0 = ptok[pb + min(r0, nvalid - 1)];
  const unsigned short* a0 = h2b + (size_t)tk0 * DMODEL + ((qx ^ s0) << 3);
#pragma unroll
  for (int p = 0; p < 3; p++) {
    size_t o = (size_t)p * 4096;
    gload16(a0 + p * 32, &L[p][0][0] + w * 512);
    stageB_chunk8(B1 + o, &L[p][1][0]);
    stageB_chunk8(B2 + o, &L[p][2][0]);
  }
  WVM6;
  BAR;
  f32x4 acc1[2][4] = {}, acc2[2][4] = {};
  int cur = 0;
  for (int kt = 0; kt < 64; kt++) {
    SCHEDBAR;
    mma16_dualB24(&L[cur][0][0], &L[cur][1][0], &L[cur][2][0], wr, wc, acc1, acc2);
    SCHEDBAR;
    BAR;
    if (kt + 3 < 64) {
      size_t o = (size_t)(kt + 3) * 4096;
      gload16(a0 + (kt + 3) * 32, &L[cur][0][0] + w * 512);
      stageB_chunk8(B1 + o, &L[cur][1][0]);
      stageB_chunk8(B2 + o, &L[cur][2][0]);
      WVM6;
    } else if (kt + 3 == 64) {
      WVM3;
    } else {
      WVM0;
    }
    BAR;
    cur = (cur == 2) ? 0 : cur + 1;
  }
  int lr = lid & 15;
  int er = wr + ((lid >> 4) << 2), ec = wc + lr;
  int ktf0 = blockIdx.x * 4;
#pragma unroll
  for (int m = 0; m < 2; m++)
#pragma unroll
    for (int n = 0; n < 4; n++)
#pragma unroll
      for (int r = 0; r < 4; r++) {
        int rl = er + m * 16 + r;
        int cc = ec + n * 16;
        float a = acc1[m][n][r];
        float s = a / (1.f + expf(-a));
        unsigned short val = (rl < nvalid) ? f2bf(s * acc2[m][n][r]) : (unsigned short)0;
        int srl = (rl ^ (rl >> 2)) & 3;
        g[((size_t)(ty * 64 + ktf0 + (cc >> 5))) * 4096 + rl * 32 +
          ((((cc & 31) >> 3) ^ srl) << 3) + (cc & 7)] = val;
      }
}

__global__ __launch_bounds__(256) void k_moe2(const unsigned short* __restrict__ gP,
                                              const unsigned short* __restrict__ wP,
                                              const int* __restrict__ ptok,
                                              const float* __restrict__ pw,
                                              const int* __restrict__ meta,
                                              float* __restrict__ out) {
  int ty = blockIdx.y;
  if (ty >= meta[25]) return;
  int tt = meta[26 + ty];
  int e = tt & 7, m0 = tt >> 3;
  int nvalid = min(128, meta[e] - m0);
  long pbase = (long)meta[16 + e] + m0;
  int kc = blockIdx.z;
  const unsigned short* Ab = gP + ((size_t)ty * 64 + kc * 32) * 4096;
  const unsigned short* Bb = wP + ((size_t)(e * 16 + blockIdx.x) * 64 + kc * 32) * 4096;
  __shared__ unsigned short L[3][2][4096];  // 48KB
  int w = threadIdx.x >> 6;
  int wr = (w >> 1) * 64, wc = (w & 1) * 64;
#pragma unroll
  for (int p = 0; p < 3; p++) {
    size_t o = (size_t)p * 4096;
    stageB_chunk(Ab + o, &L[p][0][0]);
    stageB_chunk(Bb + o, &L[p][1][0]);
  }
  WVM8;
  BAR;
  f32x4 acc[4][4] = {};
  int cur = 0;
  for (int kt = 0; kt < 32; kt++) {
    SCHEDBAR;
    mma16(&L[cur][0][0], &L[cur][1][0], wr, wc, acc);
    SCHEDBAR;
    BAR;
    if (kt + 3 < 32) {
      size_t o = (size_t)(kt + 3) * 4096;
      stageB_chunk(Ab + o, &L[cur][0][0]);
      stageB_chunk(Bb + o, &L[cur][1][0]);
      WVM8;
    } else if (kt + 3 == 32) {
      WVM4;
    } else {
      WVM0;
    }
    BAR;
    cur = (cur == 2) ? 0 : cur + 1;
  }
  int col0 = blockIdx.x * 128;
  int l = threadIdx.x & 63;
  int er = wr + ((l >> 4) << 2), ec = wc + (l & 15);
#pragma unroll
  for (int m = 0; m < 4; m++)
#pragma unroll
    for (int n = 0; n < 4; n++)
#pragma unroll
      for (int r = 0; r < 4; r++) {
        int rl = er + m * 16 + r;
        if (rl < nvalid) {
          long p = pbase + rl;
          int tk = ptok[p];
          atomicAdd(&out[(size_t)tk * DMODEL + col0 + ec + n * 16], acc[m][n][r] * pw[p]);
        }
      }
}

// ---------------- small kernels ----------------

__global__ __launch_bounds__(256) void k_ln(const float* __restrict__ x,
                                            const float* __restrict__ w,
                                            unsigned short* __restrict__ obh,
                                            unsigned short* __restrict__ obl,
                                            float* __restrict__ of, int mode) {
  int row = blockIdx.x;
  const float* xr = x + (size_t)row * DMODEL;
  float s = 0.f, ss = 0.f;
  for (int c = threadIdx.x; c < DMODEL; c += 256) {
    float v = xr[c];
    s += v; ss += v * v;
  }
#pragma unroll
  for (int o = 32; o; o >>= 1) { s += __shfl_down(s, o); ss += __shfl_down(ss, o); }
  __shared__ float rs[4], rss[4], mu_s, inv_s;
  int wid = threadIdx.x >> 6;
  if ((threadIdx.x & 63) == 0) { rs[wid] = s; rss[wid] = ss; }
  __syncthreads();
  if (threadIdx.x == 0) {
    float S1 = rs[0] + rs[1] + rs[2] + rs[3];
    float S2 = rss[0] + rss[1] + rss[2] + rss[3];
    float mu = S1 / DMODEL;
    mu_s = mu;
    inv_s = rsqrtf(S2 / DMODEL - mu * mu + 1e-5f);
  }
  __syncthreads();
  float mu = mu_s, inv = inv_s;
  int rt = row >> 7, rl = row & 127;
  int sw = (rl ^ (rl >> 2)) & 3;
  for (int c = threadIdx.x; c < DMODEL; c += 256) {
    float v = (xr[c] - mu) * inv * w[c];
    unsigned short hh, ll;
    split2(v, hh, ll);
    if (mode) {
      size_t off = ((size_t)(rt * 64 + (c >> 5))) * 4096 + rl * 32 +
                   ((((c & 31) >> 3) ^ sw) << 3) + (c & 7);
      obh[off] = hh;
      obl[off] = ll;
    } else {
      obh[(size_t)row * DMODEL + c] = hh;
      if (obl) obl[(size_t)row * DMODEL + c] = ll;
      if (of) of[(size_t)row * DMODEL + c] = v;
    }
  }
}

// RoPE: Q row-major (split), K directly in chunk layout (split)
__global__ void k_rope2(const float* __restrict__ qkv, unsigned short* __restrict__ qh,
                        unsigned short* __restrict__ ql, unsigned short* __restrict__ kPh,
                        unsigned short* __restrict__ kPl) {
  int t = blockIdx.x;
  int d = threadIdx.x;  // 0..63
  float pf = (float)pow(500000.0, (double)d * (1.0 / 64.0));
  float invf = 1.0f / pf;
  float ang = (float)t * invf;
  float cs = (float)cos((double)ang);
  float sn = (float)sin((double)ang);
  const float* row = qkv + (size_t)t * QKV_N;
  unsigned short hh, ll;
#pragma unroll
  for (int hq = 0; hq < NH; hq++) {
    float a = row[hq * HD + d], b = row[hq * HD + d + 64];
    size_t base = ((size_t)hq * S_LEN + t) * HD;
    split2(a * cs - b * sn, hh, ll); qh[base + d] = hh; ql[base + d] = ll;
    split2(b * cs + a * sn, hh, ll); qh[base + d + 64] = hh; ql[base + d + 64] = ll;
  }
  int tt2 = t >> 7, rl2 = t & 127;
  int s2 = (rl2 ^ (rl2 >> 2)) & 3;
#pragma unroll
  for (int kv = 0; kv < NKV; kv++) {
    float a = row[NH * HD + kv * HD + d], b = row[NH * HD + kv * HD + d + 64];
    float o0 = a * cs - b * sn;
    float o1 = b * cs + a * sn;
#pragma unroll
    for (int half = 0; half < 2; half++) {
      int col = d + half * 64;
      float v = half ? o1 : o0;
      size_t off = ((size_t)(kv * 64 + tt2 * 4 + (col >> 5))) * 4096 + rl2 * 32 +
                   ((((col & 31) >> 3) ^ s2) << 3) + (col & 7);
      split2(v, hh, ll);
      kPh[off] = hh;
      kPl[off] = ll;
    }
  }
}

__global__ __launch_bounds__(256) void k_router(const float* __restrict__ h2,
                                                const float* __restrict__ rw,
                                                int* __restrict__ topi,
                                                float* __restrict__ topw,
                                                int* __restrict__ cnt) {
  int t = blockIdx.x;
  __shared__ float hs[DMODEL];
  __shared__ float lg[NE];
  for (int c = threadIdx.x; c < DMODEL; c += 256) hs[c] = h2[(size_t)t * DMODEL + c];
  __syncthreads();
  int grp = threadIdx.x >> 5;
  int ln = threadIdx.x & 31;
  float p = 0.f;
  for (int c = ln; c < DMODEL; c += 32) p += hs[c] * rw[(size_t)grp * DMODEL + c];
#pragma unroll
  for (int o = 16; o; o >>= 1) p += __shfl_down(p, o, 32);
  if (ln == 0) lg[grp] = p;
  __syncthreads();
  if (threadIdx.x == 0) {
    float l0 = -3.4e38f; int i0 = 0;
    for (int e = 0; e < NE; e++)
      if (lg[e] > l0) { l0 = lg[e]; i0 = e; }
    float l1 = -3.4e38f; int i1 = 0;
    for (int e = 0; e < NE; e++)
      if (e != i0 && lg[e] > l1) { l1 = lg[e]; i1 = e; }
    float z = expf(l1 - l0);
    topi[t * 2] = i0; topi[t * 2 + 1] = i1;
    topw[t * 2] = 1.f / (1.f + z); topw[t * 2 + 1] = z / (1.f + z);
    atomicAdd(&cnt[i0], 1);
    atomicAdd(&cnt[i1], 1);
  }
}

__global__ void k_scan(int* __restrict__ meta) {
  if (threadIdx.x == 0 && blockIdx.x == 0) {
    int o = 0, nt = 0;
    for (int e = 0; e < NE; e++) {
      meta[16 + e] = o;
      for (int m0 = 0; m0 < meta[e]; m0 += 128) meta[26 + nt++] = (m0 << 3) | e;
      o += meta[e];
    }
    meta[24] = o;
    meta[25] = nt;
  }
}

__global__ void k_fill(const int* __restrict__ topi, const float* __restrict__ topw,
                       int* __restrict__ meta, int* __restrict__ ptok,
                       float* __restrict__ pw) {
  int t = blockIdx.x * blockDim.x + threadIdx.x;
  if (t >= S_LEN) return;
#pragma unroll
  for (int j = 0; j < 2; j++) {
    int e = topi[t * 2 + j];
    int p = atomicAdd(&meta[8 + e], 1);
    ptok[meta[16 + e] + p] = t;
    pw[meta[16 + e] + p] = topw[t * 2 + j];
  }
}

// ---------------- launch ----------------

extern "C" void kernel_launch(void* const* d_in, const int* in_sizes, int n_in,
                              void* d_out, int out_size, void* d_ws, size_t ws_size,
                              hipStream_t stream) {
  (void)in_sizes; (void)n_in; (void)out_size; (void)ws_size;
  const float* x = (const float*)d_in[0];
  const float* ln1w = (const float*)d_in[2];
  const float* ln2w = (const float*)d_in[3];
  const float* wqkv = (const float*)d_in[4];
  const float* wo = (const float*)d_in[5];
  const float* rw = (const float*)d_in[6];
  const float* w1 = (const float*)d_in[7];
  const float* v1 = (const float*)d_in[8];
  const float* w2 = (const float*)d_in[9];
  float* out = (float*)d_out;  // x1 after k_wo_s; MoE adds in place

  char* wsb = (char*)d_ws;
  const size_t MiB = 1u << 20;
  // ---- attention phase ----
  unsigned short* h1Ph = (unsigned short*)(wsb + 0 * MiB);     // 8 (chunks)
  unsigned short* h1Pl = (unsigned short*)(wsb + 8 * MiB);     // 8
  float* qkvb = (float*)(wsb + 16 * MiB);                      // 24
  unsigned short* qh = (unsigned short*)(wsb + 40 * MiB);      // 8
  unsigned short* ql = (unsigned short*)(wsb + 48 * MiB);      // 8
  unsigned short* vPh = (unsigned short*)(wsb + 60 * MiB);     // 2
  unsigned short* vPl = (unsigned short*)(wsb + 62 * MiB);     // 2
  unsigned short* kPh = (unsigned short*)(wsb + 64 * MiB);     // 2
  unsigned short* kPl = (unsigned short*)(wsb + 66 * MiB);     // 2
  unsigned short* atPh = (unsigned short*)(wsb + 68 * MiB);    // 8 (chunks)
  unsigned short* atPl = (unsigned short*)(wsb + 76 * MiB);    // 8
  unsigned short* wqkvPh = (unsigned short*)(wsb + 84 * MiB);  // 12
  unsigned short* wqkvPl = (unsigned short*)(wsb + 96 * MiB);  // 12
  unsigned short* woPh = (unsigned short*)(wsb + 108 * MiB);   // 8
  unsigned short* woPl = (unsigned short*)(wsb + 116 * MiB);   // 8
  // ---- MoE phase (overlays; attention buffers dead) ----
  unsigned short* h2b = (unsigned short*)(wsb + 0 * MiB);      // 8 (over h1Ph)
  unsigned short* g = (unsigned short*)(wsb + 16 * MiB);       // 20 (over qkvb)
  float* h2f = (float*)(wsb + 40 * MiB);                       // 16 (over qh/ql)
  unsigned short* wPa = (unsigned short*)(wsb + 40 * MiB);     // 64 (after router)
  unsigned short* wPb = (unsigned short*)(wsb + 104 * MiB);    // 64
  char* small = wsb + 168 * MiB;
  int* topi = (int*)small;
  float* topw = (float*)(small + 16384);
  int* ptok = (int*)(small + 32768);
  float* pw = (float*)(small + 49152);
  int* meta = (int*)(small + 65536);  // 128 ints

  // ---- pack attention weights ----
  k_pack2<<<dim3(QKV_N / 128, 16, 1), 256, 0, stream>>>(wqkv, QKV_N, 0, QKV_N / 128,
                                                        wqkvPh, wqkvPl);
  k_pack2<<<dim3(DMODEL / 128, 16, 1), 256, 0, stream>>>(wo, DMODEL, 0, DMODEL / 128,
                                                         woPh, woPl);

  // ---- attention sublayer (fp32-emulated) ----
  k_ln<<<S_LEN, 256, 0, stream>>>(x, ln1w, h1Ph, h1Pl, (float*)nullptr, 1);
  k_qkv_s<<<dim3(QKV_N / 128, S_LEN / 128), 256, 0, stream>>>(h1Ph, h1Pl, wqkvPh, wqkvPl,
                                                              qkvb);
  k_rope2<<<S_LEN, 64, 0, stream>>>(qkvb, qh, ql, kPh, kPl);
  k_pack2<<<dim3(1, 16, NKV), 256, 0, stream>>>(qkvb + (NH + NKV) * HD, QKV_N, HD, 1,
                                                vPh, vPl);
  k_flash<<<1024, 128, 0, stream>>>(qh, ql, kPh, kPl, vPh, vPl, atPh, atPl);
  k_wo_s<<<dim3(16, 16), 256, 0, stream>>>(atPh, atPl, woPh, woPl, x, out);

  // ---- MoE sublayer ----
  k_ln<<<S_LEN, 256, 0, stream>>>(out, ln2w, h2b, (unsigned short*)nullptr, h2f, 0);
  hipMemsetAsync(meta, 0, 512, stream);
  k_router<<<S_LEN, 256, 0, stream>>>(h2f, rw, topi, topw, meta);
  k_scan<<<1, 64, 0, stream>>>(meta);
  k_fill<<<8, 256, 0, stream>>>(topi, topw, meta, ptok, pw);
  k_pack1<<<dim3(16, 16, NE), 256, 0, stream>>>(w1, FF, (long)DMODEL * FF, 16, wPa);
  k_pack1<<<dim3(16, 16, NE), 256, 0, stream>>>(v1, FF, (long)DMODEL * FF, 16, wPb);
  k_moe1f<<<dim3(16, 40), 512, 0, stream>>>(h2b, ptok, wPa, wPb, meta, g);
  k_pack1<<<dim3(16, 16, NE), 256, 0, stream>>>(w2, DMODEL, (long)FF * DMODEL, 16, wPa);
  k_moe2<<<dim3(16, 40, 2), 256, 0, stream>>>(g, wPa, ptok, pw, meta, out);
}

// Round 20
// 820.459 us; speedup vs baseline: 1.0081x; 1.0081x over previous
//
#include <hip/hip_runtime.h>

#define S_LEN 2048
#define DMODEL 2048
#define NH 16
#define NKV 4
#define HD 128
#define NE 8
#define FF 2048
#define QKV_N 3072   // (H + 2*KV) * HD

typedef __attribute__((ext_vector_type(8))) short short8;
typedef __attribute__((ext_vector_type(4))) float f32x4;

__device__ inline unsigned short f2bf(float f) {
  unsigned int u = __builtin_bit_cast(unsigned int, f);
  u += 0x7fffu + ((u >> 16) & 1u);
  return (unsigned short)(u >> 16);
}
__device__ inline float bf2f(unsigned short h) {
  unsigned int u = ((unsigned int)h) << 16;
  return __builtin_bit_cast(float, u);
}
__device__ inline void split2(float v, unsigned short& h, unsigned short& l) {
  h = f2bf(v);
  l = f2bf(v - bf2f(h));
}

// ======== chunk format (verified r3-r18): 8KB = 128 rows x 32 k bf16 ========
// element (row, k=8q+j) at ushort off row*32 + ((q ^ s(row))<<3) + j, s=(row^(row>>2))&3

__device__ inline void gload16(const void* g, void* l) {
  __builtin_amdgcn_global_load_lds((const __attribute__((address_space(1))) unsigned int*)g,
                                   (__attribute__((address_space(3))) unsigned int*)l,
                                   16, 0, 0);
}
// 256-thread cooperative full-chunk stage (2 gloads/lane)
__device__ inline void stageB_chunk(const unsigned short* __restrict__ chunk,
                                    unsigned short* __restrict__ lds) {
  int w = threadIdx.x >> 6, l = threadIdx.x & 63;
  const unsigned short* s = chunk + w * 1024 + l * 8;
  unsigned short* d = lds + w * 1024;
  gload16(s, d);
  gload16(s + 512, d + 512);
}
// 512-thread cooperative full-chunk stage (1 gload/lane)
__device__ inline void stageB_chunk8(const unsigned short* __restrict__ chunk,
                                     unsigned short* __restrict__ lds) {
  int w = threadIdx.x >> 6, l = threadIdx.x & 63;
  gload16(chunk + w * 512 + l * 8, lds + w * 512);
}

#define WVM0   asm volatile("s_waitcnt vmcnt(0)" ::: "memory")
#define WVM3   asm volatile("s_waitcnt vmcnt(3)" ::: "memory")
#define WVM4   asm volatile("s_waitcnt vmcnt(4)" ::: "memory")
#define WVM6   asm volatile("s_waitcnt vmcnt(6)" ::: "memory")
#define WVM8   asm volatile("s_waitcnt vmcnt(8)" ::: "memory")
#define WVM12  asm volatile("s_waitcnt vmcnt(12)" ::: "memory")
#define WAIT_ALL  asm volatile("s_waitcnt vmcnt(0) lgkmcnt(0)" ::: "memory")
#define WAIT_LDS  asm volatile("s_waitcnt lgkmcnt(0)" ::: "memory")
#define SCHEDBAR  __builtin_amdgcn_sched_barrier(0)
#define BAR       __builtin_amdgcn_s_barrier()

// ---------------- MFMA cores ----------------

__device__ inline void mma16(const unsigned short* As, const unsigned short* Bs,
                             int wr, int wc, f32x4 acc[4][4]) {
  int l = threadIdx.x & 63;
  int lr = l & 15, lg = l >> 4;
  int qoff = ((lg ^ ((lr ^ (lr >> 2)) & 3)) << 3);
  short8 a[4], b[4];
#pragma unroll
  for (int m = 0; m < 4; m++)
    a[m] = *(const short8*)(As + (wr + m * 16 + lr) * 32 + qoff);
#pragma unroll
  for (int n = 0; n < 4; n++)
    b[n] = *(const short8*)(Bs + (wc + n * 16 + lr) * 32 + qoff);
#pragma unroll
  for (int m = 0; m < 4; m++)
#pragma unroll
    for (int n = 0; n < 4; n++)
      acc[m][n] = __builtin_amdgcn_mfma_f32_16x16x32_bf16(a[m], b[n], acc[m][n], 0, 0, 0);
}

// 8-wave variant: wave computes 32x64 (2 m-frags x 4 n-frags), dual B
__device__ inline void mma16_dualB24(const unsigned short* As, const unsigned short* Bs1,
                                     const unsigned short* Bs2, int wr, int wc,
                                     f32x4 acc1[2][4], f32x4 acc2[2][4]) {
  int l = threadIdx.x & 63;
  int lr = l & 15, lg = l >> 4;
  int qoff = ((lg ^ ((lr ^ (lr >> 2)) & 3)) << 3);
  short8 a[2], b1[4], b2[4];
#pragma unroll
  for (int m = 0; m < 2; m++)
    a[m] = *(const short8*)(As + (wr + m * 16 + lr) * 32 + qoff);
#pragma unroll
  for (int n = 0; n < 4; n++) {
    b1[n] = *(const short8*)(Bs1 + (wc + n * 16 + lr) * 32 + qoff);
    b2[n] = *(const short8*)(Bs2 + (wc + n * 16 + lr) * 32 + qoff);
  }
#pragma unroll
  for (int m = 0; m < 2; m++)
#pragma unroll
    for (int n = 0; n < 4; n++) {
      acc1[m][n] = __builtin_amdgcn_mfma_f32_16x16x32_bf16(a[m], b1[n], acc1[m][n], 0, 0, 0);
      acc2[m][n] = __builtin_amdgcn_mfma_f32_16x16x32_bf16(a[m], b2[n], acc2[m][n], 0, 0, 0);
    }
}

__device__ inline void mma16_split_reg(const unsigned short* Ash, const unsigned short* Asl,
                                       const unsigned short* Bsh, const unsigned short* Bsl,
                                       int wr, int wc, f32x4 acc[4][4]) {
  int l = threadIdx.x & 63;
  int lr = l & 15, lg = l >> 4;
  int qoff = ((lg ^ ((lr ^ (lr >> 2)) & 3)) << 3);
  short8 ah[4], al[4], bh[4], bl[4];
#pragma unroll
  for (int m = 0; m < 4; m++) {
    ah[m] = *(const short8*)(Ash + (wr + m * 16 + lr) * 32 + qoff);
    al[m] = *(const short8*)(Asl + (wr + m * 16 + lr) * 32 + qoff);
  }
#pragma unroll
  for (int n = 0; n < 4; n++) {
    bh[n] = *(const short8*)(Bsh + (wc + n * 16 + lr) * 32 + qoff);
    bl[n] = *(const short8*)(Bsl + (wc + n * 16 + lr) * 32 + qoff);
  }
#pragma unroll
  for (int m = 0; m < 4; m++)
#pragma unroll
    for (int n = 0; n < 4; n++) {
      acc[m][n] = __builtin_amdgcn_mfma_f32_16x16x32_bf16(ah[m], bh[n], acc[m][n], 0, 0, 0);
      acc[m][n] = __builtin_amdgcn_mfma_f32_16x16x32_bf16(ah[m], bl[n], acc[m][n], 0, 0, 0);
      acc[m][n] = __builtin_amdgcn_mfma_f32_16x16x32_bf16(al[m], bh[n], acc[m][n], 0, 0, 0);
    }
}

// ---------------- pack kernels ----------------

__global__ __launch_bounds__(256) void k_pack1(const float* __restrict__ src, long ld,
                                               long zs, int nc,
                                               unsigned short* __restrict__ dst) {
  __shared__ float tile[32][132];
  const float* Sp = src + (long)blockIdx.z * zs;
  int c = blockIdx.x, t = threadIdx.x;
  for (int i = 0; i < 4; i++) {
    int kt = blockIdx.y * 4 + i;
    long k0 = (long)kt * 32, n0 = (long)c * 128;
    {
      int k = t >> 3, nn = (t & 7) * 16;
      const float4* p = (const float4*)(Sp + (k0 + k) * ld + n0 + nn);
#pragma unroll
      for (int j = 0; j < 4; j++) *(float4*)&tile[k][nn + j * 4] = p[j];
    }
    __syncthreads();
    size_t cbase = ((size_t)(blockIdx.z * nc + c) * 64 + kt) * 4096;
#pragma unroll
    for (int uu = 0; uu < 2; uu++) {
      int u = t * 2 + uu;
      int n = u >> 2, qp = u & 3;
      int q = qp ^ ((n ^ (n >> 2)) & 3);
      unsigned short hb[8] __attribute__((aligned(16)));
#pragma unroll
      for (int j = 0; j < 8; j++) hb[j] = f2bf(tile[8 * q + j][n]);
      *(uint4*)(dst + cbase + u * 8) = *(const uint4*)hb;
    }
    __syncthreads();
  }
}

__global__ __launch_bounds__(256) void k_pack2(const float* __restrict__ src, long ld,
                                               long zs, int nc,
                                               unsigned short* __restrict__ dh,
                                               unsigned short* __restrict__ dl) {
  __shared__ float tile[32][132];
  const float* Sp = src + (long)blockIdx.z * zs;
  int c = blockIdx.x, t = threadIdx.x;
  for (int i = 0; i < 4; i++) {
    int kt = blockIdx.y * 4 + i;
    long k0 = (long)kt * 32, n0 = (long)c * 128;
    {
      int k = t >> 3, nn = (t & 7) * 16;
      const float4* p = (const float4*)(Sp + (k0 + k) * ld + n0 + nn);
#pragma unroll
      for (int j = 0; j < 4; j++) *(float4*)&tile[k][nn + j * 4] = p[j];
    }
    __syncthreads();
    size_t cbase = ((size_t)(blockIdx.z * nc + c) * 64 + kt) * 4096;
#pragma unroll
    for (int uu = 0; uu < 2; uu++) {
      int u = t * 2 + uu;
      int n = u >> 2, qp = u & 3;
      int q = qp ^ ((n ^ (n >> 2)) & 3);
      unsigned short hb[8] __attribute__((aligned(16)));
      unsigned short lb[8] __attribute__((aligned(16)));
#pragma unroll
      for (int j = 0; j < 8; j++) split2(tile[8 * q + j][n], hb[j], lb[j]);
      *(uint4*)(dh + cbase + u * 8) = *(const uint4*)hb;
      *(uint4*)(dl + cbase + u * 8) = *(const uint4*)lb;
    }
    __syncthreads();
  }
}

// ---------------- qkv / wo GEMMs (r15/r16 form) ----------------

__global__ __launch_bounds__(256) void k_qkv_s(const unsigned short* __restrict__ APh,
                                               const unsigned short* __restrict__ APl,
                                               const unsigned short* __restrict__ BPh,
                                               const unsigned short* __restrict__ BPl,
                                               float* __restrict__ C) {
  __shared__ unsigned short Ash[2 * 4096], Asl[2 * 4096], Bsh[2 * 4096], Bsl[2 * 4096];
  size_t ab = (size_t)blockIdx.y * 64 * 4096;
  size_t cb = (size_t)blockIdx.x * 64 * 4096;
  int w = threadIdx.x >> 6;
  int wr = (w >> 1) * 64, wc = (w & 1) * 64;
#pragma unroll
  for (int p = 0; p < 2; p++) {
    size_t o = (size_t)p * 4096;
    int b = p << 12;
    stageB_chunk(APh + ab + o, Ash + b);
    stageB_chunk(APl + ab + o, Asl + b);
    stageB_chunk(BPh + cb + o, Bsh + b);
    stageB_chunk(BPl + cb + o, Bsl + b);
  }
  WVM8;
  BAR;
  f32x4 acc[4][4] = {};
  for (int kt = 0; kt < 64; kt++) {
    int cur = (kt & 1) << 12;
    SCHEDBAR;
    mma16_split_reg(Ash + cur, Asl + cur, Bsh + cur, Bsl + cur, wr, wc, acc);
    SCHEDBAR;
    BAR;
    if (kt + 2 < 64) {
      size_t o = (size_t)(kt + 2) * 4096;
      stageB_chunk(APh + ab + o, Ash + cur);
      stageB_chunk(APl + ab + o, Asl + cur);
      stageB_chunk(BPh + cb + o, Bsh + cur);
      stageB_chunk(BPl + cb + o, Bsl + cur);
      WVM8;
    } else {
      WVM0;
    }
    BAR;
  }
  int row0 = blockIdx.y * 128, col0 = blockIdx.x * 128;
  int l = threadIdx.x & 63;
  int er = wr + ((l >> 4) << 2), ec = wc + (l & 15);
#pragma unroll
  for (int m = 0; m < 4; m++)
#pragma unroll
    for (int n = 0; n < 4; n++)
#pragma unroll
      for (int r = 0; r < 4; r++) {
        float v = acc[m][n][r];
        v = fminf(fmaxf(v, -8.f), 8.f);
        C[(size_t)(row0 + er + m * 16 + r) * QKV_N + col0 + ec + n * 16] = v;
      }
}

__global__ __launch_bounds__(256) void k_wo_s(const unsigned short* __restrict__ APh,
                                              const unsigned short* __restrict__ APl,
                                              const unsigned short* __restrict__ BPh,
                                              const unsigned short* __restrict__ BPl,
                                              const float* __restrict__ resid,
                                              float* __restrict__ x1) {
  __shared__ unsigned short Ash[2 * 4096], Asl[2 * 4096], Bsh[2 * 4096], Bsl[2 * 4096];
  size_t ab = (size_t)blockIdx.y * 64 * 4096;
  size_t cb = (size_t)blockIdx.x * 64 * 4096;
  int w = threadIdx.x >> 6;
  int wr = (w >> 1) * 64, wc = (w & 1) * 64;
#pragma unroll
  for (int p = 0; p < 2; p++) {
    size_t o = (size_t)p * 4096;
    int b = p << 12;
    stageB_chunk(APh + ab + o, Ash + b);
    stageB_chunk(APl + ab + o, Asl + b);
    stageB_chunk(BPh + cb + o, Bsh + b);
    stageB_chunk(BPl + cb + o, Bsl + b);
  }
  WVM8;
  BAR;
  f32x4 acc[4][4] = {};
  for (int kt = 0; kt < 64; kt++) {
    int cur = (kt & 1) << 12;
    SCHEDBAR;
    mma16_split_reg(Ash + cur, Asl + cur, Bsh + cur, Bsl + cur, wr, wc, acc);
    SCHEDBAR;
    BAR;
    if (kt + 2 < 64) {
      size_t o = (size_t)(kt + 2) * 4096;
      stageB_chunk(APh + ab + o, Ash + cur);
      stageB_chunk(APl + ab + o, Asl + cur);
      stageB_chunk(BPh + cb + o, Bsh + cur);
      stageB_chunk(BPl + cb + o, Bsl + cur);
      WVM8;
    } else {
      WVM0;
    }
    BAR;
  }
  int row0 = blockIdx.y * 128, col0 = blockIdx.x * 128;
  int l = threadIdx.x & 63;
  int er = wr + ((l >> 4) << 2), ec = wc + (l & 15);
#pragma unroll
  for (int m = 0; m < 4; m++)
#pragma unroll
    for (int n = 0; n < 4; n++)
#pragma unroll
      for (int r = 0; r < 4; r++) {
        size_t idx = (size_t)(row0 + er + m * 16 + r) * DMODEL + col0 + ec + n * 16;
        x1[idx] = resid[idx] + acc[m][n][r];
      }
}

// ---------------- flash attention: r16 core + 2-way K-split per block ----------------
// grid 1024; block 128 thr = 2 waves; BOTH waves cover the same 32 Q rows;
// wave w handles kt = w, w+2, ...  States merged exactly at the end via LDS.
// h = (bid&7) | ((bid>>9)<<3); rt = (bid>>3)&63; ntiles = (rt>>2)+1.

__global__ __launch_bounds__(128) void k_flash(const unsigned short* __restrict__ qh,
                                               const unsigned short* __restrict__ ql,
                                               const unsigned short* __restrict__ kPh,
                                               const unsigned short* __restrict__ kPl,
                                               const unsigned short* __restrict__ vPh,
                                               const unsigned short* __restrict__ vPl,
                                               unsigned short* __restrict__ atPh,
                                               unsigned short* __restrict__ atPl) {
  int bid = blockIdx.x;
  int h = (bid & 7) | ((bid >> 9) << 3);
  int rt = (bid >> 3) & 63;
  int kv = h >> 2;
  int ntiles = (rt >> 2) + 1;
  __shared__ float Pds[2][32 * 132];  // per-wave P scratch; reused as merge buffer
  int t = threadIdx.x;
  int w = t >> 6, l = t & 63;
  int lr = l & 15, lg = l >> 4;
  int qoff = ((lg ^ ((lr ^ (lr >> 2)) & 3)) << 3);
  int wrow0 = rt * 32;  // both waves: same 32 rows
  const unsigned short* Qbh = qh + (size_t)h * S_LEN * HD;
  const unsigned short* Qbl = ql + (size_t)h * S_LEN * HD;
  const unsigned short* Kch = kPh + (size_t)kv * 64 * 4096;
  const unsigned short* Kcl = kPl + (size_t)kv * 64 * 4096;
  const unsigned short* Vch = vPh + (size_t)kv * 64 * 4096;
  const unsigned short* Vcl = vPl + (size_t)kv * 64 * 4096;
  float* Pw = &Pds[w][0];
  float mrun[2][4], lrun[2][4];
  f32x4 Oc[2][8];
#pragma unroll
  for (int m = 0; m < 2; m++)
#pragma unroll
    for (int r = 0; r < 4; r++) { mrun[m][r] = -3.4e38f; lrun[m][r] = 0.f; }
#pragma unroll
  for (int m = 0; m < 2; m++)
#pragma unroll
    for (int n = 0; n < 8; n++)
#pragma unroll
      for (int r = 0; r < 4; r++) Oc[m][n][r] = 0.f;
  const float scale = 0.08838834764831845f;

  for (int kt = w; kt < ntiles; kt += 2) {
    f32x4 Sa[2][8];
#pragma unroll
    for (int m = 0; m < 2; m++)
#pragma unroll
      for (int n = 0; n < 8; n++)
#pragma unroll
        for (int r = 0; r < 4; r++) Sa[m][n][r] = 0.f;
#pragma unroll
    for (int kst = 0; kst < 4; kst++) {
      short8 qfh[2], qfl[2];
#pragma unroll
      for (int m = 0; m < 2; m++) {
        size_t o = (size_t)(wrow0 + m * 16 + lr) * HD + kst * 32 + lg * 8;
        qfh[m] = *(const short8*)(Qbh + o);
        qfl[m] = *(const short8*)(Qbl + o);
      }
      const unsigned short* Kh = Kch + (size_t)(kt * 4 + kst) * 4096;
      const unsigned short* Kl = Kcl + (size_t)(kt * 4 + kst) * 4096;
      short8 bh[8], bl[8];
#pragma unroll
      for (int n = 0; n < 8; n++) {
        bh[n] = *(const short8*)(Kh + (n * 16 + lr) * 32 + qoff);
        bl[n] = *(const short8*)(Kl + (n * 16 + lr) * 32 + qoff);
      }
#pragma unroll
      for (int m = 0; m < 2; m++)
#pragma unroll
        for (int n = 0; n < 8; n++) {
          Sa[m][n] = __builtin_amdgcn_mfma_f32_16x16x32_bf16(qfh[m], bh[n], Sa[m][n], 0, 0, 0);
          Sa[m][n] = __builtin_amdgcn_mfma_f32_16x16x32_bf16(qfh[m], bl[n], Sa[m][n], 0, 0, 0);
          Sa[m][n] = __builtin_amdgcn_mfma_f32_16x16x32_bf16(qfl[m], bh[n], Sa[m][n], 0, 0, 0);
        }
    }
#pragma unroll
    for (int m = 0; m < 2; m++)
#pragma unroll
      for (int r = 0; r < 4; r++) {
        int row = wrow0 + m * 16 + lg * 4 + r;
        float mx = mrun[m][r];
#pragma unroll
        for (int n = 0; n < 8; n++) {
          float v = Sa[m][n][r] * scale;
          int col = kt * 128 + n * 16 + lr;
          v = (col <= row) ? v : -3.4e38f;
          Sa[m][n][r] = v;
          mx = fmaxf(mx, v);
        }
        mx = fmaxf(mx, __shfl_xor(mx, 1));
        mx = fmaxf(mx, __shfl_xor(mx, 2));
        mx = fmaxf(mx, __shfl_xor(mx, 4));
        mx = fmaxf(mx, __shfl_xor(mx, 8));
        float al_ = expf(mrun[m][r] - mx);
        float sum = 0.f;
#pragma unroll
        for (int n = 0; n < 8; n++) {
          float v = Sa[m][n][r];
          float e = (v > -1.0e37f) ? expf(v - mx) : 0.f;
          Sa[m][n][r] = e;
          sum += e;
        }
        sum += __shfl_xor(sum, 1);
        sum += __shfl_xor(sum, 2);
        sum += __shfl_xor(sum, 4);
        sum += __shfl_xor(sum, 8);
        lrun[m][r] = lrun[m][r] * al_ + sum;
        mrun[m][r] = mx;
#pragma unroll
        for (int n = 0; n < 8; n++) Oc[m][n][r] *= al_;
      }
    WAIT_LDS;
    SCHEDBAR;
#pragma unroll
    for (int m = 0; m < 2; m++)
#pragma unroll
      for (int n = 0; n < 8; n++)
#pragma unroll
        for (int r = 0; r < 4; r++)
          Pw[(m * 16 + lg * 4 + r) * 132 + n * 16 + lr] = Sa[m][n][r];
    WAIT_LDS;
    SCHEDBAR;
#pragma unroll
    for (int kst = 0; kst < 4; kst++) {
      const unsigned short* Vh = Vch + (size_t)(kt * 4 + kst) * 4096;
      const unsigned short* Vl = Vcl + (size_t)(kt * 4 + kst) * 4096;
      short8 bh[8], bl[8];
#pragma unroll
      for (int n = 0; n < 8; n++) {
        bh[n] = *(const short8*)(Vh + (n * 16 + lr) * 32 + qoff);
        bl[n] = *(const short8*)(Vl + (n * 16 + lr) * 32 + qoff);
      }
#pragma unroll
      for (int m = 0; m < 2; m++) {
        const float* pp = &Pw[(m * 16 + lr) * 132 + kst * 32 + lg * 8];
        unsigned short ahb[8] __attribute__((aligned(16)));
        unsigned short alb[8] __attribute__((aligned(16)));
#pragma unroll
        for (int j = 0; j < 8; j++) split2(pp[j], ahb[j], alb[j]);
        short8 ah = *(const short8*)ahb;
        short8 al_ = *(const short8*)alb;
#pragma unroll
        for (int n = 0; n < 8; n++) {
          Oc[m][n] = __builtin_amdgcn_mfma_f32_16x16x32_bf16(ah, bh[n], Oc[m][n], 0, 0, 0);
          Oc[m][n] = __builtin_amdgcn_mfma_f32_16x16x32_bf16(ah, bl[n], Oc[m][n], 0, 0, 0);
          Oc[m][n] = __builtin_amdgcn_mfma_f32_16x16x32_bf16(al_, bh[n], Oc[m][n], 0, 0, 0);
        }
      }
    }
  }
  // ---- merge wave1's partial state into wave0, then epilogue (wave0 only) ----
  __syncthreads();
  if (w == 1) {
#pragma unroll
    for (int m = 0; m < 2; m++) {
      int rowl = m * 16 + lg * 4;
#pragma unroll
      for (int n = 0; n < 8; n++)
#pragma unroll
        for (int r = 0; r < 4; r++)
          Pds[1][(rowl + r) * 132 + n * 16 + lr] = Oc[m][n][r];
      if (lr == 0) {
#pragma unroll
        for (int r = 0; r < 4; r++) {
          Pds[0][rowl + r] = mrun[m][r];
          Pds[0][32 + rowl + r] = lrun[m][r];
        }
      }
    }
  }
  __syncthreads();
  if (w == 0) {
#pragma unroll
    for (int m = 0; m < 2; m++)
#pragma unroll
      for (int r = 0; r < 4; r++) {
        int rowl = m * 16 + lg * 4 + r;
        int row = wrow0 + rowl;
        float mB = Pds[0][rowl];
        float lB = Pds[0][32 + rowl];
        float mm = fmaxf(mrun[m][r], mB);
        float eA = expf(mrun[m][r] - mm);
        float eB = (mB > -1.0e37f) ? expf(mB - mm) : 0.f;
        float lv = lrun[m][r] * eA + lB * eB;
        int rtc = row >> 7, rl = row & 127;
        int sr = (rl ^ (rl >> 2)) & 3;
#pragma unroll
        for (int n = 0; n < 8; n++) {
          float ov = Oc[m][n][r] * eA + Pds[1][rowl * 132 + n * 16 + lr] * eB;
          int col = h * HD + n * 16 + lr;
          size_t off = ((size_t)(rtc * 64 + (col >> 5))) * 4096 + rl * 32 +
                       ((((col & 31) >> 3) ^ sr) << 3) + (col & 7);
          unsigned short hh, ll;
          split2(ov / lv, hh, ll);
          atPh[off] = hh;
          atPl[off] = ll;
        }
      }
  }
}

// ---------------- MoE GEMMs ----------------

// moe1f: 8-wave (512 thr), wave = 32x64 quadrant; depth-3 counted vmcnt
__global__ __launch_bounds__(512, 4) void k_moe1f(const unsigned short* __restrict__ h2b,
                                                  const int* __restrict__ ptok,
                                                  const unsigned short* __restrict__ wPa,
                                                  const unsigned short* __restrict__ wPb,
                                                  const int* __restrict__ meta,
                                                  unsigned short* __restrict__ g) {
  int ty = blockIdx.y;
  if (ty >= meta[25]) return;
  int tt = meta[26 + ty];
  int e = tt & 7, m0 = tt >> 3;
  int nvalid = min(128, meta[e] - m0);
  const unsigned short* B1 = wPa + (size_t)(e * 16 + blockIdx.x) * 64 * 4096;
  const unsigned short* B2 = wPb + (size_t)(e * 16 + blockIdx.x) * 64 * 4096;
  __shared__ unsigned short L[3][3][4096];  // 72KB
  int tid = threadIdx.x;
  int w = tid >> 6;
  int lid = tid & 63;
  int wr = (w & 3) * 32, wc = (w >> 2) * 64;
  int r0 = w * 16 + (lid >> 2);
  int qx = lid & 3;
  int s0 = (r0 ^ (r0 >> 2)) & 3;
  long pb = (long)meta[16 + e] + m0;
  int tk0 = ptok[pb + min(r0, nvalid - 1)];
  const unsigned short* a0 = h2b + (size_t)tk0 * DMODEL + ((qx ^ s0) << 3);
#pragma unroll
  for (int p = 0; p < 3; p++) {
    size_t o = (size_t)p * 4096;
    gload16(a0 + p * 32, &L[p][0][0] + w * 512);
    stageB_chunk8(B1 + o, &L[p][1][0]);
    stageB_chunk8(B2 + o, &L[p][2][0]);
  }
  WVM6;
  BAR;
  f32x4 acc1[2][4] = {}, acc2[2][4] = {};
  int cur = 0;
  for (int kt = 0; kt < 64; kt++) {
    SCHEDBAR;
    mma16_dualB24(&L[cur][0][0], &L[cur][1][0], &L[cur][2][0], wr, wc, acc1, acc2);
    SCHEDBAR;
    BAR;
    if (kt + 3 < 64) {
      size_t o = (size_t)(kt + 3) * 4096;
      gload16(a0 + (kt + 3) * 32, &L[cur][0][0] + w * 512);
      stageB_chunk8(B1 + o, &L[cur][1][0]);
      stageB_chunk8(B2 + o, &L[cur][2][0]);
      WVM6;
    } else if (kt + 3 == 64) {
      WVM3;
    } else {
      WVM0;
    }
    BAR;
    cur = (cur == 2) ? 0 : cur + 1;
  }
  int lr = lid & 15;
  int er = wr + ((lid >> 4) << 2), ec = wc + lr;
  int ktf0 = blockIdx.x * 4;
#pragma unroll
  for (int m = 0; m < 2; m++)
#pragma unroll
    for (int n = 0; n < 4; n++)
#pragma unroll
      for (int r = 0; r < 4; r++) {
        int rl = er + m * 16 + r;
        int cc = ec + n * 16;
        float a = acc1[m][n][r];
        float s = a / (1.f + expf(-a));
        unsigned short val = (rl < nvalid) ? f2bf(s * acc2[m][n][r]) : (unsigned short)0;
        int srl = (rl ^ (rl >> 2)) & 3;
        g[((size_t)(ty * 64 + ktf0 + (cc >> 5))) * 4096 + rl * 32 +
          ((((cc & 31) >> 3) ^ srl) << 3) + (cc & 7)] = val;
      }
}

__global__ __launch_bounds__(256) void k_moe2(const unsigned short* __restrict__ gP,
                                              const unsigned short* __restrict__ wP,
                                              const int* __restrict__ ptok,
                                              const float* __restrict__ pw,
                                              const int* __restrict__ meta,
                                              float* __restrict__ out) {
  int ty = blockIdx.y;
  if (ty >= meta[25]) return;
  int tt = meta[26 + ty];
  int e = tt & 7, m0 = tt >> 3;
  int nvalid = min(128, meta[e] - m0);
  long pbase = (long)meta[16 + e] + m0;
  int kc = blockIdx.z;
  const unsigned short* Ab = gP + ((size_t)ty * 64 + kc * 32) * 4096;
  const unsigned short* Bb = wP + ((size_t)(e * 16 + blockIdx.x) * 64 + kc * 32) * 4096;
  __shared__ unsigned short L[3][2][4096];  // 48KB
  int w = threadIdx.x >> 6;
  int wr = (w >> 1) * 64, wc = (w & 1) * 64;
#pragma unroll
  for (int p = 0; p < 3; p++) {
    size_t o = (size_t)p * 4096;
    stageB_chunk(Ab + o, &L[p][0][0]);
    stageB_chunk(Bb + o, &L[p][1][0]);
  }
  WVM8;
  BAR;
  f32x4 acc[4][4] = {};
  int cur = 0;
  for (int kt = 0; kt < 32; kt++) {
    SCHEDBAR;
    mma16(&L[cur][0][0], &L[cur][1][0], wr, wc, acc);
    SCHEDBAR;
    BAR;
    if (kt + 3 < 32) {
      size_t o = (size_t)(kt + 3) * 4096;
      stageB_chunk(Ab + o, &L[cur][0][0]);
      stageB_chunk(Bb + o, &L[cur][1][0]);
      WVM8;
    } else if (kt + 3 == 32) {
      WVM4;
    } else {
      WVM0;
    }
    BAR;
    cur = (cur == 2) ? 0 : cur + 1;
  }
  int col0 = blockIdx.x * 128;
  int l = threadIdx.x & 63;
  int er = wr + ((l >> 4) << 2), ec = wc + (l & 15);
#pragma unroll
  for (int m = 0; m < 4; m++)
#pragma unroll
    for (int n = 0; n < 4; n++)
#pragma unroll
      for (int r = 0; r < 4; r++) {
        int rl = er + m * 16 + r;
        if (rl < nvalid) {
          long p = pbase + rl;
          int tk = ptok[p];
          atomicAdd(&out[(size_t)tk * DMODEL + col0 + ec + n * 16], acc[m][n][r] * pw[p]);
        }
      }
}

// ---------------- small kernels ----------------

__global__ __launch_bounds__(256) void k_ln(const float* __restrict__ x,
                                            const float* __restrict__ w,
                                            unsigned short* __restrict__ obh,
                                            unsigned short* __restrict__ obl,
                                            float* __restrict__ of, int mode) {
  int row = blockIdx.x;
  const float* xr = x + (size_t)row * DMODEL;
  float s = 0.f, ss = 0.f;
  for (int c = threadIdx.x; c < DMODEL; c += 256) {
    float v = xr[c];
    s += v; ss += v * v;
  }
#pragma unroll
  for (int o = 32; o; o >>= 1) { s += __shfl_down(s, o); ss += __shfl_down(ss, o); }
  __shared__ float rs[4], rss[4], mu_s, inv_s;
  int wid = threadIdx.x >> 6;
  if ((threadIdx.x & 63) == 0) { rs[wid] = s; rss[wid] = ss; }
  __syncthreads();
  if (threadIdx.x == 0) {
    float S1 = rs[0] + rs[1] + rs[2] + rs[3];
    float S2 = rss[0] + rss[1] + rss[2] + rss[3];
    float mu = S1 / DMODEL;
    mu_s = mu;
    inv_s = rsqrtf(S2 / DMODEL - mu * mu + 1e-5f);
  }
  __syncthreads();
  float mu = mu_s, inv = inv_s;
  int rt = row >> 7, rl = row & 127;
  int sw = (rl ^ (rl >> 2)) & 3;
  for (int c = threadIdx.x; c < DMODEL; c += 256) {
    float v = (xr[c] - mu) * inv * w[c];
    unsigned short hh, ll;
    split2(v, hh, ll);
    if (mode) {
      size_t off = ((size_t)(rt * 64 + (c >> 5))) * 4096 + rl * 32 +
                   ((((c & 31) >> 3) ^ sw) << 3) + (c & 7);
      obh[off] = hh;
      obl[off] = ll;
    } else {
      obh[(size_t)row * DMODEL + c] = hh;
      if (obl) obl[(size_t)row * DMODEL + c] = ll;
      if (of) of[(size_t)row * DMODEL + c] = v;
    }
  }
}

// RoPE: Q row-major (split), K directly in chunk layout (split)
__global__ void k_rope2(const float* __restrict__ qkv, unsigned short* __restrict__ qh,
                        unsigned short* __restrict__ ql, unsigned short* __restrict__ kPh,
                        unsigned short* __restrict__ kPl) {
  int t = blockIdx.x;
  int d = threadIdx.x;  // 0..63
  float pf = (float)pow(500000.0, (double)d * (1.0 / 64.0));
  float invf = 1.0f / pf;
  float ang = (float)t * invf;
  float cs = (float)cos((double)ang);
  float sn = (float)sin((double)ang);
  const float* row = qkv + (size_t)t * QKV_N;
  unsigned short hh, ll;
#pragma unroll
  for (int hq = 0; hq < NH; hq++) {
    float a = row[hq * HD + d], b = row[hq * HD + d + 64];
    size_t base = ((size_t)hq * S_LEN + t) * HD;
    split2(a * cs - b * sn, hh, ll); qh[base + d] = hh; ql[base + d] = ll;
    split2(b * cs + a * sn, hh, ll); qh[base + d + 64] = hh; ql[base + d + 64] = ll;
  }
  int tt2 = t >> 7, rl2 = t & 127;
  int s2 = (rl2 ^ (rl2 >> 2)) & 3;
#pragma unroll
  for (int kv = 0; kv < NKV; kv++) {
    float a = row[NH * HD + kv * HD + d], b = row[NH * HD + kv * HD + d + 64];
    float o0 = a * cs - b * sn;
    float o1 = b * cs + a * sn;
#pragma unroll
    for (int half = 0; half < 2; half++) {
      int col = d + half * 64;
      float v = half ? o1 : o0;
      size_t off = ((size_t)(kv * 64 + tt2 * 4 + (col >> 5))) * 4096 + rl2 * 32 +
                   ((((col & 31) >> 3) ^ s2) << 3) + (col & 7);
      split2(v, hh, ll);
      kPh[off] = hh;
      kPl[off] = ll;
    }
  }
}

__global__ __launch_bounds__(256) void k_router(const float* __restrict__ h2,
                                                const float* __restrict__ rw,
                                                int* __restrict__ topi,
                                                float* __restrict__ topw,
                                                int* __restrict__ cnt) {
  int t = blockIdx.x;
  __shared__ float hs[DMODEL];
  __shared__ float lg[NE];
  for (int c = threadIdx.x; c < DMODEL; c += 256) hs[c] = h2[(size_t)t * DMODEL + c];
  __syncthreads();
  int grp = threadIdx.x >> 5;
  int ln = threadIdx.x & 31;
  float p = 0.f;
  for (int c = ln; c < DMODEL; c += 32) p += hs[c] * rw[(size_t)grp * DMODEL + c];
#pragma unroll
  for (int o = 16; o; o >>= 1) p += __shfl_down(p, o, 32);
  if (ln == 0) lg[grp] = p;
  __syncthreads();
  if (threadIdx.x == 0) {
    float l0 = -3.4e38f; int i0 = 0;
    for (int e = 0; e < NE; e++)
      if (lg[e] > l0) { l0 = lg[e]; i0 = e; }
    float l1 = -3.4e38f; int i1 = 0;
    for (int e = 0; e < NE; e++)
      if (e != i0 && lg[e] > l1) { l1 = lg[e]; i1 = e; }
    float z = expf(l1 - l0);
    topi[t * 2] = i0; topi[t * 2 + 1] = i1;
    topw[t * 2] = 1.f / (1.f + z); topw[t * 2 + 1] = z / (1.f + z);
    atomicAdd(&cnt[i0], 1);
    atomicAdd(&cnt[i1], 1);
  }
}

__global__ void k_scan(int* __restrict__ meta) {
  if (threadIdx.x == 0 && blockIdx.x == 0) {
    int o = 0, nt = 0;
    for (int e = 0; e < NE; e++) {
      meta[16 + e] = o;
      for (int m0 = 0; m0 < meta[e]; m0 += 128) meta[26 + nt++] = (m0 << 3) | e;
      o += meta[e];
    }
    meta[24] = o;
    meta[25] = nt;
  }
}

__global__ void k_fill(const int* __restrict__ topi, const float* __restrict__ topw,
                       int* __restrict__ meta, int* __restrict__ ptok,
                       float* __restrict__ pw) {
  int t = blockIdx.x * blockDim.x + threadIdx.x;
  if (t >= S_LEN) return;
#pragma unroll
  for (int j = 0; j < 2; j++) {
    int e = topi[t * 2 + j];
    int p = atomicAdd(&meta[8 + e], 1);
    ptok[meta[16 + e] + p] = t;
    pw[meta[16 + e] + p] = topw[t * 2 + j];
  }
}

// ---------------- launch ----------------

extern "C" void kernel_launch(void* const* d_in, const int* in_sizes, int n_in,
                              void* d_out, int out_size, void* d_ws, size_t ws_size,
                              hipStream_t stream) {
  (void)in_sizes; (void)n_in; (void)out_size; (void)ws_size;
  const float* x = (const float*)d_in[0];
  const float* ln1w = (const float*)d_in[2];
  const float* ln2w = (const float*)d_in[3];
  const float* wqkv = (const float*)d_in[4];
  const float* wo = (const float*)d_in[5];
  const float* rw = (const float*)d_in[6];
  const float* w1 = (const float*)d_in[7];
  const float* v1 = (const float*)d_in[8];
  const float* w2 = (const float*)d_in[9];
  float* out = (float*)d_out;  // x1 after k_wo_s; MoE adds in place

  char* wsb = (char*)d_ws;
  const size_t MiB = 1u << 20;
  // ---- attention phase ----
  unsigned short* h1Ph = (unsigned short*)(wsb + 0 * MiB);     // 8 (chunks)
  unsigned short* h1Pl = (unsigned short*)(wsb + 8 * MiB);     // 8
  float* qkvb = (float*)(wsb + 16 * MiB);                      // 24
  unsigned short* qh = (unsigned short*)(wsb + 40 * MiB);      // 8
  unsigned short* ql = (unsigned short*)(wsb + 48 * MiB);      // 8
  unsigned short* vPh = (unsigned short*)(wsb + 60 * MiB);     // 2
  unsigned short* vPl = (unsigned short*)(wsb + 62 * MiB);     // 2
  unsigned short* kPh = (unsigned short*)(wsb + 64 * MiB);     // 2
  unsigned short* kPl = (unsigned short*)(wsb + 66 * MiB);     // 2
  unsigned short* atPh = (unsigned short*)(wsb + 68 * MiB);    // 8 (chunks)
  unsigned short* atPl = (unsigned short*)(wsb + 76 * MiB);    // 8
  unsigned short* wqkvPh = (unsigned short*)(wsb + 84 * MiB);  // 12
  unsigned short* wqkvPl = (unsigned short*)(wsb + 96 * MiB);  // 12
  unsigned short* woPh = (unsigned short*)(wsb + 108 * MiB);   // 8
  unsigned short* woPl = (unsigned short*)(wsb + 116 * MiB);   // 8
  // ---- MoE phase (overlays; attention buffers dead) ----
  unsigned short* h2b = (unsigned short*)(wsb + 0 * MiB);      // 8 (over h1Ph)
  unsigned short* g = (unsigned short*)(wsb + 16 * MiB);       // 20 (over qkvb)
  float* h2f = (float*)(wsb + 40 * MiB);                       // 16 (over qh/ql)
  unsigned short* wPa = (unsigned short*)(wsb + 40 * MiB);     // 64 (after router)
  unsigned short* wPb = (unsigned short*)(wsb + 104 * MiB);    // 64
  char* small = wsb + 168 * MiB;
  int* topi = (int*)small;
  float* topw = (float*)(small + 16384);
  int* ptok = (int*)(small + 32768);
  float* pw = (float*)(small + 49152);
  int* meta = (int*)(small + 65536);  // 128 ints

  // ---- pack attention weights ----
  k_pack2<<<dim3(QKV_N / 128, 16, 1), 256, 0, stream>>>(wqkv, QKV_N, 0, QKV_N / 128,
                                                        wqkvPh, wqkvPl);
  k_pack2<<<dim3(DMODEL / 128, 16, 1), 256, 0, stream>>>(wo, DMODEL, 0, DMODEL / 128,
                                                         woPh, woPl);

  // ---- attention sublayer (fp32-emulated) ----
  k_ln<<<S_LEN, 256, 0, stream>>>(x, ln1w, h1Ph, h1Pl, (float*)nullptr, 1);
  k_qkv_s<<<dim3(QKV_N / 128, S_LEN / 128), 256, 0, stream>>>(h1Ph, h1Pl, wqkvPh, wqkvPl,
                                                              qkvb);
  k_rope2<<<S_LEN, 64, 0, stream>>>(qkvb, qh, ql, kPh, kPl);
  k_pack2<<<dim3(1, 16, NKV), 256, 0, stream>>>(qkvb + (NH + NKV) * HD, QKV_N, HD, 1,
                                                vPh, vPl);
  k_flash<<<1024, 128, 0, stream>>>(qh, ql, kPh, kPl, vPh, vPl, atPh, atPl);
  k_wo_s<<<dim3(16, 16), 256, 0, stream>>>(atPh, atPl, woPh, woPl, x, out);

  // ---- MoE sublayer ----
  k_ln<<<S_LEN, 256, 0, stream>>>(out, ln2w, h2b, (unsigned short*)nullptr, h2f, 0);
  hipMemsetAsync(meta, 0, 512, stream);
  k_router<<<S_LEN, 256, 0, stream>>>(h2f, rw, topi, topw, meta);
  k_scan<<<1, 64, 0, stream>>>(meta);
  k_fill<<<8, 256, 0, stream>>>(topi, topw, meta, ptok, pw);
  k_pack1<<<dim3(16, 16, NE), 256, 0, stream>>>(w1, FF, (long)DMODEL * FF, 16, wPa);
  k_pack1<<<dim3(16, 16, NE), 256, 0, stream>>>(v1, FF, (long)DMODEL * FF, 16, wPb);
  k_moe1f<<<dim3(16, 40), 512, 0, stream>>>(h2b, ptok, wPa, wPb, meta, g);
  k_pack1<<<dim3(16, 16, NE), 256, 0, stream>>>(w2, DMODEL, (long)FF * DMODEL, 16, wPa);
  k_moe2<<<dim3(16, 40, 2), 256, 0, stream>>>(g, wPa, ptok, pw, meta, out);
}

// Round 21
// 781.665 us; speedup vs baseline: 1.0581x; 1.0496x over previous
//
#include <hip/hip_runtime.h>

#define S_LEN 2048
#define DMODEL 2048
#define NH 16
#define NKV 4
#define HD 128
#define NE 8
#define FF 2048
#define QKV_N 3072   // (H + 2*KV) * HD

typedef __attribute__((ext_vector_type(8))) short short8;
typedef __attribute__((ext_vector_type(4))) float f32x4;

__device__ inline unsigned short f2bf(float f) {
  unsigned int u = __builtin_bit_cast(unsigned int, f);
  u += 0x7fffu + ((u >> 16) & 1u);
  return (unsigned short)(u >> 16);
}
__device__ inline float bf2f(unsigned short h) {
  unsigned int u = ((unsigned int)h) << 16;
  return __builtin_bit_cast(float, u);
}
__device__ inline void split2(float v, unsigned short& h, unsigned short& l) {
  h = f2bf(v);
  l = f2bf(v - bf2f(h));
}

// ======== chunk format (verified r3-r20): 8KB = 128 rows x 32 k bf16 ========
// element (row, k=8q+j) at ushort off row*32 + ((q ^ s(row))<<3) + j, s=(row^(row>>2))&3

__device__ inline void gload16(const void* g, void* l) {
  __builtin_amdgcn_global_load_lds((const __attribute__((address_space(1))) unsigned int*)g,
                                   (__attribute__((address_space(3))) unsigned int*)l,
                                   16, 0, 0);
}
// 256-thread cooperative full-chunk stage (2 gloads/lane)
__device__ inline void stageB_chunk(const unsigned short* __restrict__ chunk,
                                    unsigned short* __restrict__ lds) {
  int w = threadIdx.x >> 6, l = threadIdx.x & 63;
  const unsigned short* s = chunk + w * 1024 + l * 8;
  unsigned short* d = lds + w * 1024;
  gload16(s, d);
  gload16(s + 512, d + 512);
}
// 512-thread cooperative full-chunk stage (1 gload/lane)
__device__ inline void stageB_chunk8(const unsigned short* __restrict__ chunk,
                                     unsigned short* __restrict__ lds) {
  int w = threadIdx.x >> 6, l = threadIdx.x & 63;
  gload16(chunk + w * 512 + l * 8, lds + w * 512);
}

#define WVM0   asm volatile("s_waitcnt vmcnt(0)" ::: "memory")
#define WVM3   asm volatile("s_waitcnt vmcnt(3)" ::: "memory")
#define WVM4   asm volatile("s_waitcnt vmcnt(4)" ::: "memory")
#define WVM6   asm volatile("s_waitcnt vmcnt(6)" ::: "memory")
#define WVM8   asm volatile("s_waitcnt vmcnt(8)" ::: "memory")
#define WVM12  asm volatile("s_waitcnt vmcnt(12)" ::: "memory")
#define WAIT_ALL  asm volatile("s_waitcnt vmcnt(0) lgkmcnt(0)" ::: "memory")
#define WAIT_LDS  asm volatile("s_waitcnt lgkmcnt(0)" ::: "memory")
#define SCHEDBAR  __builtin_amdgcn_sched_barrier(0)
#define BAR       __builtin_amdgcn_s_barrier()

// ---------------- MFMA cores ----------------

__device__ inline void mma16(const unsigned short* As, const unsigned short* Bs,
                             int wr, int wc, f32x4 acc[4][4]) {
  int l = threadIdx.x & 63;
  int lr = l & 15, lg = l >> 4;
  int qoff = ((lg ^ ((lr ^ (lr >> 2)) & 3)) << 3);
  short8 a[4], b[4];
#pragma unroll
  for (int m = 0; m < 4; m++)
    a[m] = *(const short8*)(As + (wr + m * 16 + lr) * 32 + qoff);
#pragma unroll
  for (int n = 0; n < 4; n++)
    b[n] = *(const short8*)(Bs + (wc + n * 16 + lr) * 32 + qoff);
#pragma unroll
  for (int m = 0; m < 4; m++)
#pragma unroll
    for (int n = 0; n < 4; n++)
      acc[m][n] = __builtin_amdgcn_mfma_f32_16x16x32_bf16(a[m], b[n], acc[m][n], 0, 0, 0);
}

// 8-wave variant: wave computes 32x64 (2 m-frags x 4 n-frags), dual B
__device__ inline void mma16_dualB24(const unsigned short* As, const unsigned short* Bs1,
                                     const unsigned short* Bs2, int wr, int wc,
                                     f32x4 acc1[2][4], f32x4 acc2[2][4]) {
  int l = threadIdx.x & 63;
  int lr = l & 15, lg = l >> 4;
  int qoff = ((lg ^ ((lr ^ (lr >> 2)) & 3)) << 3);
  short8 a[2], b1[4], b2[4];
#pragma unroll
  for (int m = 0; m < 2; m++)
    a[m] = *(const short8*)(As + (wr + m * 16 + lr) * 32 + qoff);
#pragma unroll
  for (int n = 0; n < 4; n++) {
    b1[n] = *(const short8*)(Bs1 + (wc + n * 16 + lr) * 32 + qoff);
    b2[n] = *(const short8*)(Bs2 + (wc + n * 16 + lr) * 32 + qoff);
  }
#pragma unroll
  for (int m = 0; m < 2; m++)
#pragma unroll
    for (int n = 0; n < 4; n++) {
      acc1[m][n] = __builtin_amdgcn_mfma_f32_16x16x32_bf16(a[m], b1[n], acc1[m][n], 0, 0, 0);
      acc2[m][n] = __builtin_amdgcn_mfma_f32_16x16x32_bf16(a[m], b2[n], acc2[m][n], 0, 0, 0);
    }
}

__device__ inline void mma16_split_reg(const unsigned short* Ash, const unsigned short* Asl,
                                       const unsigned short* Bsh, const unsigned short* Bsl,
                                       int wr, int wc, f32x4 acc[4][4]) {
  int l = threadIdx.x & 63;
  int lr = l & 15, lg = l >> 4;
  int qoff = ((lg ^ ((lr ^ (lr >> 2)) & 3)) << 3);
  short8 ah[4], al[4], bh[4], bl[4];
#pragma unroll
  for (int m = 0; m < 4; m++) {
    ah[m] = *(const short8*)(Ash + (wr + m * 16 + lr) * 32 + qoff);
    al[m] = *(const short8*)(Asl + (wr + m * 16 + lr) * 32 + qoff);
  }
#pragma unroll
  for (int n = 0; n < 4; n++) {
    bh[n] = *(const short8*)(Bsh + (wc + n * 16 + lr) * 32 + qoff);
    bl[n] = *(const short8*)(Bsl + (wc + n * 16 + lr) * 32 + qoff);
  }
#pragma unroll
  for (int m = 0; m < 4; m++)
#pragma unroll
    for (int n = 0; n < 4; n++) {
      acc[m][n] = __builtin_amdgcn_mfma_f32_16x16x32_bf16(ah[m], bh[n], acc[m][n], 0, 0, 0);
      acc[m][n] = __builtin_amdgcn_mfma_f32_16x16x32_bf16(ah[m], bl[n], acc[m][n], 0, 0, 0);
      acc[m][n] = __builtin_amdgcn_mfma_f32_16x16x32_bf16(al[m], bh[n], acc[m][n], 0, 0, 0);
    }
}

// ---------------- pack kernels ----------------

__global__ __launch_bounds__(256) void k_pack1(const float* __restrict__ src, long ld,
                                               long zs, int nc,
                                               unsigned short* __restrict__ dst) {
  __shared__ float tile[32][132];
  const float* Sp = src + (long)blockIdx.z * zs;
  int c = blockIdx.x, t = threadIdx.x;
  for (int i = 0; i < 4; i++) {
    int kt = blockIdx.y * 4 + i;
    long k0 = (long)kt * 32, n0 = (long)c * 128;
    {
      int k = t >> 3, nn = (t & 7) * 16;
      const float4* p = (const float4*)(Sp + (k0 + k) * ld + n0 + nn);
#pragma unroll
      for (int j = 0; j < 4; j++) *(float4*)&tile[k][nn + j * 4] = p[j];
    }
    __syncthreads();
    size_t cbase = ((size_t)(blockIdx.z * nc + c) * 64 + kt) * 4096;
#pragma unroll
    for (int uu = 0; uu < 2; uu++) {
      int u = t * 2 + uu;
      int n = u >> 2, qp = u & 3;
      int q = qp ^ ((n ^ (n >> 2)) & 3);
      unsigned short hb[8] __attribute__((aligned(16)));
#pragma unroll
      for (int j = 0; j < 8; j++) hb[j] = f2bf(tile[8 * q + j][n]);
      *(uint4*)(dst + cbase + u * 8) = *(const uint4*)hb;
    }
    __syncthreads();
  }
}

__global__ __launch_bounds__(256) void k_pack2(const float* __restrict__ src, long ld,
                                               long zs, int nc,
                                               unsigned short* __restrict__ dh,
                                               unsigned short* __restrict__ dl) {
  __shared__ float tile[32][132];
  const float* Sp = src + (long)blockIdx.z * zs;
  int c = blockIdx.x, t = threadIdx.x;
  for (int i = 0; i < 4; i++) {
    int kt = blockIdx.y * 4 + i;
    long k0 = (long)kt * 32, n0 = (long)c * 128;
    {
      int k = t >> 3, nn = (t & 7) * 16;
      const float4* p = (const float4*)(Sp + (k0 + k) * ld + n0 + nn);
#pragma unroll
      for (int j = 0; j < 4; j++) *(float4*)&tile[k][nn + j * 4] = p[j];
    }
    __syncthreads();
    size_t cbase = ((size_t)(blockIdx.z * nc + c) * 64 + kt) * 4096;
#pragma unroll
    for (int uu = 0; uu < 2; uu++) {
      int u = t * 2 + uu;
      int n = u >> 2, qp = u & 3;
      int q = qp ^ ((n ^ (n >> 2)) & 3);
      unsigned short hb[8] __attribute__((aligned(16)));
      unsigned short lb[8] __attribute__((aligned(16)));
#pragma unroll
      for (int j = 0; j < 8; j++) split2(tile[8 * q + j][n], hb[j], lb[j]);
      *(uint4*)(dh + cbase + u * 8) = *(const uint4*)hb;
      *(uint4*)(dl + cbase + u * 8) = *(const uint4*)lb;
    }
    __syncthreads();
  }
}

// ---------------- qkv / wo GEMMs (r15/r16 form) ----------------

__global__ __launch_bounds__(256) void k_qkv_s(const unsigned short* __restrict__ APh,
                                               const unsigned short* __restrict__ APl,
                                               const unsigned short* __restrict__ BPh,
                                               const unsigned short* __restrict__ BPl,
                                               float* __restrict__ C) {
  __shared__ unsigned short Ash[2 * 4096], Asl[2 * 4096], Bsh[2 * 4096], Bsl[2 * 4096];
  size_t ab = (size_t)blockIdx.y * 64 * 4096;
  size_t cb = (size_t)blockIdx.x * 64 * 4096;
  int w = threadIdx.x >> 6;
  int wr = (w >> 1) * 64, wc = (w & 1) * 64;
#pragma unroll
  for (int p = 0; p < 2; p++) {
    size_t o = (size_t)p * 4096;
    int b = p << 12;
    stageB_chunk(APh + ab + o, Ash + b);
    stageB_chunk(APl + ab + o, Asl + b);
    stageB_chunk(BPh + cb + o, Bsh + b);
    stageB_chunk(BPl + cb + o, Bsl + b);
  }
  WVM8;
  BAR;
  f32x4 acc[4][4] = {};
  for (int kt = 0; kt < 64; kt++) {
    int cur = (kt & 1) << 12;
    SCHEDBAR;
    mma16_split_reg(Ash + cur, Asl + cur, Bsh + cur, Bsl + cur, wr, wc, acc);
    SCHEDBAR;
    BAR;
    if (kt + 2 < 64) {
      size_t o = (size_t)(kt + 2) * 4096;
      stageB_chunk(APh + ab + o, Ash + cur);
      stageB_chunk(APl + ab + o, Asl + cur);
      stageB_chunk(BPh + cb + o, Bsh + cur);
      stageB_chunk(BPl + cb + o, Bsl + cur);
      WVM8;
    } else {
      WVM0;
    }
    BAR;
  }
  int row0 = blockIdx.y * 128, col0 = blockIdx.x * 128;
  int l = threadIdx.x & 63;
  int er = wr + ((l >> 4) << 2), ec = wc + (l & 15);
#pragma unroll
  for (int m = 0; m < 4; m++)
#pragma unroll
    for (int n = 0; n < 4; n++)
#pragma unroll
      for (int r = 0; r < 4; r++) {
        float v = acc[m][n][r];
        v = fminf(fmaxf(v, -8.f), 8.f);
        C[(size_t)(row0 + er + m * 16 + r) * QKV_N + col0 + ec + n * 16] = v;
      }
}

__global__ __launch_bounds__(256) void k_wo_s(const unsigned short* __restrict__ APh,
                                              const unsigned short* __restrict__ APl,
                                              const unsigned short* __restrict__ BPh,
                                              const unsigned short* __restrict__ BPl,
                                              const float* __restrict__ resid,
                                              float* __restrict__ x1) {
  __shared__ unsigned short Ash[2 * 4096], Asl[2 * 4096], Bsh[2 * 4096], Bsl[2 * 4096];
  size_t ab = (size_t)blockIdx.y * 64 * 4096;
  size_t cb = (size_t)blockIdx.x * 64 * 4096;
  int w = threadIdx.x >> 6;
  int wr = (w >> 1) * 64, wc = (w & 1) * 64;
#pragma unroll
  for (int p = 0; p < 2; p++) {
    size_t o = (size_t)p * 4096;
    int b = p << 12;
    stageB_chunk(APh + ab + o, Ash + b);
    stageB_chunk(APl + ab + o, Asl + b);
    stageB_chunk(BPh + cb + o, Bsh + b);
    stageB_chunk(BPl + cb + o, Bsl + b);
  }
  WVM8;
  BAR;
  f32x4 acc[4][4] = {};
  for (int kt = 0; kt < 64; kt++) {
    int cur = (kt & 1) << 12;
    SCHEDBAR;
    mma16_split_reg(Ash + cur, Asl + cur, Bsh + cur, Bsl + cur, wr, wc, acc);
    SCHEDBAR;
    BAR;
    if (kt + 2 < 64) {
      size_t o = (size_t)(kt + 2) * 4096;
      stageB_chunk(APh + ab + o, Ash + cur);
      stageB_chunk(APl + ab + o, Asl + cur);
      stageB_chunk(BPh + cb + o, Bsh + cur);
      stageB_chunk(BPl + cb + o, Bsl + cur);
      WVM8;
    } else {
      WVM0;
    }
    BAR;
  }
  int row0 = blockIdx.y * 128, col0 = blockIdx.x * 128;
  int l = threadIdx.x & 63;
  int er = wr + ((l >> 4) << 2), ec = wc + (l & 15);
#pragma unroll
  for (int m = 0; m < 4; m++)
#pragma unroll
    for (int n = 0; n < 4; n++)
#pragma unroll
      for (int r = 0; r < 4; r++) {
        size_t idx = (size_t)(row0 + er + m * 16 + r) * DMODEL + col0 + ec + n * 16;
        x1[idx] = resid[idx] + acc[m][n][r];
      }
}

// ---------------- flash attention: r18 core + longest-job-first block order ----------------
// grid 1024; block 128 thr = 2 waves; BOTH waves cover the same 32 Q rows;
// wave w handles kt = w, w+2, ...  States merged exactly at the end via LDS.
// h = (bid&7) | ((bid>>9)<<3); rt = 63 - ((bid>>3)&63)  <- heavy tiles dispatch FIRST.

__global__ __launch_bounds__(128) void k_flash(const unsigned short* __restrict__ qh,
                                               const unsigned short* __restrict__ ql,
                                               const unsigned short* __restrict__ kPh,
                                               const unsigned short* __restrict__ kPl,
                                               const unsigned short* __restrict__ vPh,
                                               const unsigned short* __restrict__ vPl,
                                               unsigned short* __restrict__ atPh,
                                               unsigned short* __restrict__ atPl) {
  int bid = blockIdx.x;
  int h = (bid & 7) | ((bid >> 9) << 3);
  int rt = 63 - ((bid >> 3) & 63);  // longest-job-first: rt=63 (16 tiles) at bid 0
  int kv = h >> 2;
  int ntiles = (rt >> 2) + 1;
  __shared__ float Pds[2][32 * 132];  // per-wave P scratch; reused as merge buffer
  int t = threadIdx.x;
  int w = t >> 6, l = t & 63;
  int lr = l & 15, lg = l >> 4;
  int qoff = ((lg ^ ((lr ^ (lr >> 2)) & 3)) << 3);
  int wrow0 = rt * 32;  // both waves: same 32 rows
  const unsigned short* Qbh = qh + (size_t)h * S_LEN * HD;
  const unsigned short* Qbl = ql + (size_t)h * S_LEN * HD;
  const unsigned short* Kch = kPh + (size_t)kv * 64 * 4096;
  const unsigned short* Kcl = kPl + (size_t)kv * 64 * 4096;
  const unsigned short* Vch = vPh + (size_t)kv * 64 * 4096;
  const unsigned short* Vcl = vPl + (size_t)kv * 64 * 4096;
  float* Pw = &Pds[w][0];
  float mrun[2][4], lrun[2][4];
  f32x4 Oc[2][8];
#pragma unroll
  for (int m = 0; m < 2; m++)
#pragma unroll
    for (int r = 0; r < 4; r++) { mrun[m][r] = -3.4e38f; lrun[m][r] = 0.f; }
#pragma unroll
  for (int m = 0; m < 2; m++)
#pragma unroll
    for (int n = 0; n < 8; n++)
#pragma unroll
      for (int r = 0; r < 4; r++) Oc[m][n][r] = 0.f;
  const float scale = 0.08838834764831845f;

  for (int kt = w; kt < ntiles; kt += 2) {
    f32x4 Sa[2][8];
#pragma unroll
    for (int m = 0; m < 2; m++)
#pragma unroll
      for (int n = 0; n < 8; n++)
#pragma unroll
        for (int r = 0; r < 4; r++) Sa[m][n][r] = 0.f;
#pragma unroll
    for (int kst = 0; kst < 4; kst++) {
      short8 qfh[2], qfl[2];
#pragma unroll
      for (int m = 0; m < 2; m++) {
        size_t o = (size_t)(wrow0 + m * 16 + lr) * HD + kst * 32 + lg * 8;
        qfh[m] = *(const short8*)(Qbh + o);
        qfl[m] = *(const short8*)(Qbl + o);
      }
      const unsigned short* Kh = Kch + (size_t)(kt * 4 + kst) * 4096;
      const unsigned short* Kl = Kcl + (size_t)(kt * 4 + kst) * 4096;
      short8 bh[8], bl[8];
#pragma unroll
      for (int n = 0; n < 8; n++) {
        bh[n] = *(const short8*)(Kh + (n * 16 + lr) * 32 + qoff);
        bl[n] = *(const short8*)(Kl + (n * 16 + lr) * 32 + qoff);
      }
#pragma unroll
      for (int m = 0; m < 2; m++)
#pragma unroll
        for (int n = 0; n < 8; n++) {
          Sa[m][n] = __builtin_amdgcn_mfma_f32_16x16x32_bf16(qfh[m], bh[n], Sa[m][n], 0, 0, 0);
          Sa[m][n] = __builtin_amdgcn_mfma_f32_16x16x32_bf16(qfh[m], bl[n], Sa[m][n], 0, 0, 0);
          Sa[m][n] = __builtin_amdgcn_mfma_f32_16x16x32_bf16(qfl[m], bh[n], Sa[m][n], 0, 0, 0);
        }
    }
#pragma unroll
    for (int m = 0; m < 2; m++)
#pragma unroll
      for (int r = 0; r < 4; r++) {
        int row = wrow0 + m * 16 + lg * 4 + r;
        float mx = mrun[m][r];
#pragma unroll
        for (int n = 0; n < 8; n++) {
          float v = Sa[m][n][r] * scale;
          int col = kt * 128 + n * 16 + lr;
          v = (col <= row) ? v : -3.4e38f;
          Sa[m][n][r] = v;
          mx = fmaxf(mx, v);
        }
        mx = fmaxf(mx, __shfl_xor(mx, 1));
        mx = fmaxf(mx, __shfl_xor(mx, 2));
        mx = fmaxf(mx, __shfl_xor(mx, 4));
        mx = fmaxf(mx, __shfl_xor(mx, 8));
        float al_ = expf(mrun[m][r] - mx);
        float sum = 0.f;
#pragma unroll
        for (int n = 0; n < 8; n++) {
          float v = Sa[m][n][r];
          float e = (v > -1.0e37f) ? expf(v - mx) : 0.f;
          Sa[m][n][r] = e;
          sum += e;
        }
        sum += __shfl_xor(sum, 1);
        sum += __shfl_xor(sum, 2);
        sum += __shfl_xor(sum, 4);
        sum += __shfl_xor(sum, 8);
        lrun[m][r] = lrun[m][r] * al_ + sum;
        mrun[m][r] = mx;
#pragma unroll
        for (int n = 0; n < 8; n++) Oc[m][n][r] *= al_;
      }
    WAIT_LDS;
    SCHEDBAR;
#pragma unroll
    for (int m = 0; m < 2; m++)
#pragma unroll
      for (int n = 0; n < 8; n++)
#pragma unroll
        for (int r = 0; r < 4; r++)
          Pw[(m * 16 + lg * 4 + r) * 132 + n * 16 + lr] = Sa[m][n][r];
    WAIT_LDS;
    SCHEDBAR;
#pragma unroll
    for (int kst = 0; kst < 4; kst++) {
      const unsigned short* Vh = Vch + (size_t)(kt * 4 + kst) * 4096;
      const unsigned short* Vl = Vcl + (size_t)(kt * 4 + kst) * 4096;
      short8 bh[8], bl[8];
#pragma unroll
      for (int n = 0; n < 8; n++) {
        bh[n] = *(const short8*)(Vh + (n * 16 + lr) * 32 + qoff);
        bl[n] = *(const short8*)(Vl + (n * 16 + lr) * 32 + qoff);
      }
#pragma unroll
      for (int m = 0; m < 2; m++) {
        const float* pp = &Pw[(m * 16 + lr) * 132 + kst * 32 + lg * 8];
        unsigned short ahb[8] __attribute__((aligned(16)));
        unsigned short alb[8] __attribute__((aligned(16)));
#pragma unroll
        for (int j = 0; j < 8; j++) split2(pp[j], ahb[j], alb[j]);
        short8 ah = *(const short8*)ahb;
        short8 al_ = *(const short8*)alb;
#pragma unroll
        for (int n = 0; n < 8; n++) {
          Oc[m][n] = __builtin_amdgcn_mfma_f32_16x16x32_bf16(ah, bh[n], Oc[m][n], 0, 0, 0);
          Oc[m][n] = __builtin_amdgcn_mfma_f32_16x16x32_bf16(ah, bl[n], Oc[m][n], 0, 0, 0);
          Oc[m][n] = __builtin_amdgcn_mfma_f32_16x16x32_bf16(al_, bh[n], Oc[m][n], 0, 0, 0);
        }
      }
    }
  }
  // ---- merge wave1's partial state into wave0, then epilogue (wave0 only) ----
  __syncthreads();
  if (w == 1) {
#pragma unroll
    for (int m = 0; m < 2; m++) {
      int rowl = m * 16 + lg * 4;
#pragma unroll
      for (int n = 0; n < 8; n++)
#pragma unroll
        for (int r = 0; r < 4; r++)
          Pds[1][(rowl + r) * 132 + n * 16 + lr] = Oc[m][n][r];
      if (lr == 0) {
#pragma unroll
        for (int r = 0; r < 4; r++) {
          Pds[0][rowl + r] = mrun[m][r];
          Pds[0][32 + rowl + r] = lrun[m][r];
        }
      }
    }
  }
  __syncthreads();
  if (w == 0) {
#pragma unroll
    for (int m = 0; m < 2; m++)
#pragma unroll
      for (int r = 0; r < 4; r++) {
        int rowl = m * 16 + lg * 4 + r;
        int row = wrow0 + rowl;
        float mB = Pds[0][rowl];
        float lB = Pds[0][32 + rowl];
        float mm = fmaxf(mrun[m][r], mB);
        float eA = expf(mrun[m][r] - mm);
        float eB = (mB > -1.0e37f) ? expf(mB - mm) : 0.f;
        float lv = lrun[m][r] * eA + lB * eB;
        int rtc = row >> 7, rl = row & 127;
        int sr = (rl ^ (rl >> 2)) & 3;
#pragma unroll
        for (int n = 0; n < 8; n++) {
          float ov = Oc[m][n][r] * eA + Pds[1][rowl * 132 + n * 16 + lr] * eB;
          int col = h * HD + n * 16 + lr;
          size_t off = ((size_t)(rtc * 64 + (col >> 5))) * 4096 + rl * 32 +
                       ((((col & 31) >> 3) ^ sr) << 3) + (col & 7);
          unsigned short hh, ll;
          split2(ov / lv, hh, ll);
          atPh[off] = hh;
          atPl[off] = ll;
        }
      }
  }
}

// ---------------- MoE GEMMs ----------------

// moe1f: 8-wave (512 thr), wave = 32x64 quadrant; depth-3 counted vmcnt
__global__ __launch_bounds__(512, 4) void k_moe1f(const unsigned short* __restrict__ h2b,
                                                  const int* __restrict__ ptok,
                                                  const unsigned short* __restrict__ wPa,
                                                  const unsigned short* __restrict__ wPb,
                                                  const int* __restrict__ meta,
                                                  unsigned short* __restrict__ g) {
  int ty = blockIdx.y;
  if (ty >= meta[25]) return;
  int tt = meta[26 + ty];
  int e = tt & 7, m0 = tt >> 3;
  int nvalid = min(128, meta[e] - m0);
  const unsigned short* B1 = wPa + (size_t)(e * 16 + blockIdx.x) * 64 * 4096;
  const unsigned short* B2 = wPb + (size_t)(e * 16 + blockIdx.x) * 64 * 4096;
  __shared__ unsigned short L[3][3][4096];  // 72KB
  int tid = threadIdx.x;
  int w = tid >> 6;
  int lid = tid & 63;
  int wr = (w & 3) * 32, wc = (w >> 2) * 64;
  int r0 = w * 16 + (lid >> 2);
  int qx = lid & 3;
  int s0 = (r0 ^ (r0 >> 2)) & 3;
  long pb = (long)meta[16 + e] + m0;
  int tk0 = ptok[pb + min(r0, nvalid - 1)];
  const unsigned short* a0 = h2b + (size_t)tk0 * DMODEL + ((qx ^ s0) << 3);
#pragma unroll
  for (int p = 0; p < 3; p++) {
    size_t o = (size_t)p * 4096;
    gload16(a0 + p * 32, &L[p][0][0] + w * 512);
    stageB_chunk8(B1 + o, &L[p][1][0]);
    stageB_chunk8(B2 + o, &L[p][2][0]);
  }
  WVM6;
  BAR;
  f32x4 acc1[2][4] = {}, acc2[2][4] = {};
  int cur = 0;
  for (int kt = 0; kt < 64; kt++) {
    SCHEDBAR;
    mma16_dualB24(&L[cur][0][0], &L[cur][1][0], &L[cur][2][0], wr, wc, acc1, acc2);
    SCHEDBAR;
    BAR;
    if (kt + 3 < 64) {
      size_t o = (size_t)(kt + 3) * 4096;
      gload16(a0 + (kt + 3) * 32, &L[cur][0][0] + w * 512);
      stageB_chunk8(B1 + o, &L[cur][1][0]);
      stageB_chunk8(B2 + o, &L[cur][2][0]);
      WVM6;
    } else if (kt + 3 == 64) {
      WVM3;
    } else {
      WVM0;
    }
    BAR;
    cur = (cur == 2) ? 0 : cur + 1;
  }
  int lr = lid & 15;
  int er = wr + ((lid >> 4) << 2), ec = wc + lr;
  int ktf0 = blockIdx.x * 4;
#pragma unroll
  for (int m = 0; m < 2; m++)
#pragma unroll
    for (int n = 0; n < 4; n++)
#pragma unroll
      for (int r = 0; r < 4; r++) {
        int rl = er + m * 16 + r;
        int cc = ec + n * 16;
        float a = acc1[m][n][r];
        float s = a / (1.f + expf(-a));
        unsigned short val = (rl < nvalid) ? f2bf(s * acc2[m][n][r]) : (unsigned short)0;
        int srl = (rl ^ (rl >> 2)) & 3;
        g[((size_t)(ty * 64 + ktf0 + (cc >> 5))) * 4096 + rl * 32 +
          ((((cc & 31) >> 3) ^ srl) << 3) + (cc & 7)] = val;
      }
}

__global__ __launch_bounds__(256) void k_moe2(const unsigned short* __restrict__ gP,
                                              const unsigned short* __restrict__ wP,
                                              const int* __restrict__ ptok,
                                              const float* __restrict__ pw,
                                              const int* __restrict__ meta,
                                              float* __restrict__ out) {
  int ty = blockIdx.y;
  if (ty >= meta[25]) return;
  int tt = meta[26 + ty];
  int e = tt & 7, m0 = tt >> 3;
  int nvalid = min(128, meta[e] - m0);
  long pbase = (long)meta[16 + e] + m0;
  int kc = blockIdx.z;
  const unsigned short* Ab = gP + ((size_t)ty * 64 + kc * 32) * 4096;
  const unsigned short* Bb = wP + ((size_t)(e * 16 + blockIdx.x) * 64 + kc * 32) * 4096;
  __shared__ unsigned short L[3][2][4096];  // 48KB
  int w = threadIdx.x >> 6;
  int wr = (w >> 1) * 64, wc = (w & 1) * 64;
#pragma unroll
  for (int p = 0; p < 3; p++) {
    size_t o = (size_t)p * 4096;
    stageB_chunk(Ab + o, &L[p][0][0]);
    stageB_chunk(Bb + o, &L[p][1][0]);
  }
  WVM8;
  BAR;
  f32x4 acc[4][4] = {};
  int cur = 0;
  for (int kt = 0; kt < 32; kt++) {
    SCHEDBAR;
    mma16(&L[cur][0][0], &L[cur][1][0], wr, wc, acc);
    SCHEDBAR;
    BAR;
    if (kt + 3 < 32) {
      size_t o = (size_t)(kt + 3) * 4096;
      stageB_chunk(Ab + o, &L[cur][0][0]);
      stageB_chunk(Bb + o, &L[cur][1][0]);
      WVM8;
    } else if (kt + 3 == 32) {
      WVM4;
    } else {
      WVM0;
    }
    BAR;
    cur = (cur == 2) ? 0 : cur + 1;
  }
  int col0 = blockIdx.x * 128;
  int l = threadIdx.x & 63;
  int er = wr + ((l >> 4) << 2), ec = wc + (l & 15);
#pragma unroll
  for (int m = 0; m < 4; m++)
#pragma unroll
    for (int n = 0; n < 4; n++)
#pragma unroll
      for (int r = 0; r < 4; r++) {
        int rl = er + m * 16 + r;
        if (rl < nvalid) {
          long p = pbase + rl;
          int tk = ptok[p];
          atomicAdd(&out[(size_t)tk * DMODEL + col0 + ec + n * 16], acc[m][n][r] * pw[p]);
        }
      }
}

// ---------------- small kernels ----------------

__global__ __launch_bounds__(256) void k_ln(const float* __restrict__ x,
                                            const float* __restrict__ w,
                                            unsigned short* __restrict__ obh,
                                            unsigned short* __restrict__ obl,
                                            float* __restrict__ of, int mode) {
  int row = blockIdx.x;
  const float* xr = x + (size_t)row * DMODEL;
  float s = 0.f, ss = 0.f;
  for (int c = threadIdx.x; c < DMODEL; c += 256) {
    float v = xr[c];
    s += v; ss += v * v;
  }
#pragma unroll
  for (int o = 32; o; o >>= 1) { s += __shfl_down(s, o); ss += __shfl_down(ss, o); }
  __shared__ float rs[4], rss[4], mu_s, inv_s;
  int wid = threadIdx.x >> 6;
  if ((threadIdx.x & 63) == 0) { rs[wid] = s; rss[wid] = ss; }
  __syncthreads();
  if (threadIdx.x == 0) {
    float S1 = rs[0] + rs[1] + rs[2] + rs[3];
    float S2 = rss[0] + rss[1] + rss[2] + rss[3];
    float mu = S1 / DMODEL;
    mu_s = mu;
    inv_s = rsqrtf(S2 / DMODEL - mu * mu + 1e-5f);
  }
  __syncthreads();
  float mu = mu_s, inv = inv_s;
  int rt = row >> 7, rl = row & 127;
  int sw = (rl ^ (rl >> 2)) & 3;
  for (int c = threadIdx.x; c < DMODEL; c += 256) {
    float v = (xr[c] - mu) * inv * w[c];
    unsigned short hh, ll;
    split2(v, hh, ll);
    if (mode) {
      size_t off = ((size_t)(rt * 64 + (c >> 5))) * 4096 + rl * 32 +
                   ((((c & 31) >> 3) ^ sw) << 3) + (c & 7);
      obh[off] = hh;
      obl[off] = ll;
    } else {
      obh[(size_t)row * DMODEL + c] = hh;
      if (obl) obl[(size_t)row * DMODEL + c] = ll;
      if (of) of[(size_t)row * DMODEL + c] = v;
    }
  }
}

// RoPE: Q row-major (split), K directly in chunk layout (split)
__global__ void k_rope2(const float* __restrict__ qkv, unsigned short* __restrict__ qh,
                        unsigned short* __restrict__ ql, unsigned short* __restrict__ kPh,
                        unsigned short* __restrict__ kPl) {
  int t = blockIdx.x;
  int d = threadIdx.x;  // 0..63
  float pf = (float)pow(500000.0, (double)d * (1.0 / 64.0));
  float invf = 1.0f / pf;
  float ang = (float)t * invf;
  float cs = (float)cos((double)ang);
  float sn = (float)sin((double)ang);
  const float* row = qkv + (size_t)t * QKV_N;
  unsigned short hh, ll;
#pragma unroll
  for (int hq = 0; hq < NH; hq++) {
    float a = row[hq * HD + d], b = row[hq * HD + d + 64];
    size_t base = ((size_t)hq * S_LEN + t) * HD;
    split2(a * cs - b * sn, hh, ll); qh[base + d] = hh; ql[base + d] = ll;
    split2(b * cs + a * sn, hh, ll); qh[base + d + 64] = hh; ql[base + d + 64] = ll;
  }
  int tt2 = t >> 7, rl2 = t & 127;
  int s2 = (rl2 ^ (rl2 >> 2)) & 3;
#pragma unroll
  for (int kv = 0; kv < NKV; kv++) {
    float a = row[NH * HD + kv * HD + d], b = row[NH * HD + kv * HD + d + 64];
    float o0 = a * cs - b * sn;
    float o1 = b * cs + a * sn;
#pragma unroll
    for (int half = 0; half < 2; half++) {
      int col = d + half * 64;
      float v = half ? o1 : o0;
      size_t off = ((size_t)(kv * 64 + tt2 * 4 + (col >> 5))) * 4096 + rl2 * 32 +
                   ((((col & 31) >> 3) ^ s2) << 3) + (col & 7);
      split2(v, hh, ll);
      kPh[off] = hh;
      kPl[off] = ll;
    }
  }
}

__global__ __launch_bounds__(256) void k_router(const float* __restrict__ h2,
                                                const float* __restrict__ rw,
                                                int* __restrict__ topi,
                                                float* __restrict__ topw,
                                                int* __restrict__ cnt) {
  int t = blockIdx.x;
  __shared__ float hs[DMODEL];
  __shared__ float lg[NE];
  for (int c = threadIdx.x; c < DMODEL; c += 256) hs[c] = h2[(size_t)t * DMODEL + c];
  __syncthreads();
  int grp = threadIdx.x >> 5;
  int ln = threadIdx.x & 31;
  float p = 0.f;
  for (int c = ln; c < DMODEL; c += 32) p += hs[c] * rw[(size_t)grp * DMODEL + c];
#pragma unroll
  for (int o = 16; o; o >>= 1) p += __shfl_down(p, o, 32);
  if (ln == 0) lg[grp] = p;
  __syncthreads();
  if (threadIdx.x == 0) {
    float l0 = -3.4e38f; int i0 = 0;
    for (int e = 0; e < NE; e++)
      if (lg[e] > l0) { l0 = lg[e]; i0 = e; }
    float l1 = -3.4e38f; int i1 = 0;
    for (int e = 0; e < NE; e++)
      if (e != i0 && lg[e] > l1) { l1 = lg[e]; i1 = e; }
    float z = expf(l1 - l0);
    topi[t * 2] = i0; topi[t * 2 + 1] = i1;
    topw[t * 2] = 1.f / (1.f + z); topw[t * 2 + 1] = z / (1.f + z);
    atomicAdd(&cnt[i0], 1);
    atomicAdd(&cnt[i1], 1);
  }
}

__global__ void k_scan(int* __restrict__ meta) {
  if (threadIdx.x == 0 && blockIdx.x == 0) {
    int o = 0, nt = 0;
    for (int e = 0; e < NE; e++) {
      meta[16 + e] = o;
      for (int m0 = 0; m0 < meta[e]; m0 += 128) meta[26 + nt++] = (m0 << 3) | e;
      o += meta[e];
    }
    meta[24] = o;
    meta[25] = nt;
  }
}

__global__ void k_fill(const int* __restrict__ topi, const float* __restrict__ topw,
                       int* __restrict__ meta, int* __restrict__ ptok,
                       float* __restrict__ pw) {
  int t = blockIdx.x * blockDim.x + threadIdx.x;
  if (t >= S_LEN) return;
#pragma unroll
  for (int j = 0; j < 2; j++) {
    int e = topi[t * 2 + j];
    int p = atomicAdd(&meta[8 + e], 1);
    ptok[meta[16 + e] + p] = t;
    pw[meta[16 + e] + p] = topw[t * 2 + j];
  }
}

// ---------------- launch ----------------

extern "C" void kernel_launch(void* const* d_in, const int* in_sizes, int n_in,
                              void* d_out, int out_size, void* d_ws, size_t ws_size,
                              hipStream_t stream) {
  (void)in_sizes; (void)n_in; (void)out_size; (void)ws_size;
  const float* x = (const float*)d_in[0];
  const float* ln1w = (const float*)d_in[2];
  const float* ln2w = (const float*)d_in[3];
  const float* wqkv = (const float*)d_in[4];
  const float* wo = (const float*)d_in[5];
  const float* rw = (const float*)d_in[6];
  const float* w1 = (const float*)d_in[7];
  const float* v1 = (const float*)d_in[8];
  const float* w2 = (const float*)d_in[9];
  float* out = (float*)d_out;  // x1 after k_wo_s; MoE adds in place

  char* wsb = (char*)d_ws;
  const size_t MiB = 1u << 20;
  // ---- attention phase ----
  unsigned short* h1Ph = (unsigned short*)(wsb + 0 * MiB);     // 8 (chunks)
  unsigned short* h1Pl = (unsigned short*)(wsb + 8 * MiB);     // 8
  float* qkvb = (float*)(wsb + 16 * MiB);                      // 24
  unsigned short* qh = (unsigned short*)(wsb + 40 * MiB);      // 8
  unsigned short* ql = (unsigned short*)(wsb + 48 * MiB);      // 8
  unsigned short* vPh = (unsigned short*)(wsb + 60 * MiB);     // 2
  unsigned short* vPl = (unsigned short*)(wsb + 62 * MiB);     // 2
  unsigned short* kPh = (unsigned short*)(wsb + 64 * MiB);     // 2
  unsigned short* kPl = (unsigned short*)(wsb + 66 * MiB);     // 2
  unsigned short* atPh = (unsigned short*)(wsb + 68 * MiB);    // 8 (chunks)
  unsigned short* atPl = (unsigned short*)(wsb + 76 * MiB);    // 8
  unsigned short* wqkvPh = (unsigned short*)(wsb + 84 * MiB);  // 12
  unsigned short* wqkvPl = (unsigned short*)(wsb + 96 * MiB);  // 12
  unsigned short* woPh = (unsigned short*)(wsb + 108 * MiB);   // 8
  unsigned short* woPl = (unsigned short*)(wsb + 116 * MiB);   // 8
  // ---- MoE phase (overlays; attention buffers dead) ----
  unsigned short* h2b = (unsigned short*)(wsb + 0 * MiB);      // 8 (over h1Ph)
  unsigned short* g = (unsigned short*)(wsb + 16 * MiB);       // 20 (over qkvb)
  float* h2f = (float*)(wsb + 40 * MiB);                       // 16 (over qh/ql)
  unsigned short* wPa = (unsigned short*)(wsb + 40 * MiB);     // 64 (after router)
  unsigned short* wPb = (unsigned short*)(wsb + 104 * MiB);    // 64
  char* small = wsb + 168 * MiB;
  int* topi = (int*)small;
  float* topw = (float*)(small + 16384);
  int* ptok = (int*)(small + 32768);
  float* pw = (float*)(small + 49152);
  int* meta = (int*)(small + 65536);  // 128 ints

  // ---- pack attention weights ----
  k_pack2<<<dim3(QKV_N / 128, 16, 1), 256, 0, stream>>>(wqkv, QKV_N, 0, QKV_N / 128,
                                                        wqkvPh, wqkvPl);
  k_pack2<<<dim3(DMODEL / 128, 16, 1), 256, 0, stream>>>(wo, DMODEL, 0, DMODEL / 128,
                                                         woPh, woPl);

  // ---- attention sublayer (fp32-emulated) ----
  k_ln<<<S_LEN, 256, 0, stream>>>(x, ln1w, h1Ph, h1Pl, (float*)nullptr, 1);
  k_qkv_s<<<dim3(QKV_N / 128, S_LEN / 128), 256, 0, stream>>>(h1Ph, h1Pl, wqkvPh, wqkvPl,
                                                              qkvb);
  k_rope2<<<S_LEN, 64, 0, stream>>>(qkvb, qh, ql, kPh, kPl);
  k_pack2<<<dim3(1, 16, NKV), 256, 0, stream>>>(qkvb + (NH + NKV) * HD, QKV_N, HD, 1,
                                                vPh, vPl);
  k_flash<<<1024, 128, 0, stream>>>(qh, ql, kPh, kPl, vPh, vPl, atPh, atPl);
  k_wo_s<<<dim3(16, 16), 256, 0, stream>>>(atPh, atPl, woPh, woPl, x, out);

  // ---- MoE sublayer ----
  k_ln<<<S_LEN, 256, 0, stream>>>(out, ln2w, h2b, (unsigned short*)nullptr, h2f, 0);
  hipMemsetAsync(meta, 0, 512, stream);
  k_router<<<S_LEN, 256, 0, stream>>>(h2f, rw, topi, topw, meta);
  k_scan<<<1, 64, 0, stream>>>(meta);
  k_fill<<<8, 256, 0, stream>>>(topi, topw, meta, ptok, pw);
  k_pack1<<<dim3(16, 16, NE), 256, 0, stream>>>(w1, FF, (long)DMODEL * FF, 16, wPa);
  k_pack1<<<dim3(16, 16, NE), 256, 0, stream>>>(v1, FF, (long)DMODEL * FF, 16, wPb);
  k_moe1f<<<dim3(16, 40), 512, 0, stream>>>(h2b, ptok, wPa, wPb, meta, g);
  k_pack1<<<dim3(16, 16, NE), 256, 0, stream>>>(w2, DMODEL, (long)FF * DMODEL, 16, wPa);
  k_moe2<<<dim3(16, 40, 2), 256, 0, stream>>>(g, wPa, ptok, pw, meta, out);
}